// Round 15
// baseline (996.320 us; speedup 1.0000x reference)
//
#include <hip/hip_runtime.h>
#include <hip/hip_bf16.h>

#define NWAY 20
#define NSHOT 5
#define NT 8
#define NDIM 640
#define NSEM 300
#define NSEMH 150
#define NCLS 351
#define NXY 121
#define NWT 160   // NWAY*NT, indexed wt = w*8 + t

typedef short s16x8 __attribute__((ext_vector_type(8)));
typedef float f32x4 __attribute__((ext_vector_type(4)));
typedef float f32x4u __attribute__((ext_vector_type(4), aligned(4)));

__device__ __forceinline__ float sigmoidf_(float x) { return 1.0f / (1.0f + expf(-x)); }
__device__ __forceinline__ float lreluf_(float x) { return x >= 0.0f ? x : 0.1f * x; }
__device__ __forceinline__ float invl2_(float ss) { return 1.0f / fmaxf(sqrtf(ss), 1e-12f); }

__device__ __forceinline__ unsigned bfr_(float f) {
    unsigned b = __float_as_uint(f);
    return (b + 0x7FFFu + ((b >> 16) & 1u)) >> 16;   // RNE to bf16
}
__device__ __forceinline__ unsigned pkbf_(float a, float b) { return bfr_(a) | (bfr_(b) << 16); }

__device__ __forceinline__ s16x8 cvt8_(const float* p) {
    f32x4u a = *(const f32x4u*)p;
    f32x4u b = *(const f32x4u*)(p + 4);
    union { unsigned u[4]; s16x8 v; } r;
    r.u[0] = pkbf_(a[0], a[1]); r.u[1] = pkbf_(a[2], a[3]);
    r.u[2] = pkbf_(b[0], b[1]); r.u[3] = pkbf_(b[2], b[3]);
    return r.v;
}

__device__ __forceinline__ float waveReduceSum(float v) {
#pragma unroll
    for (int off = 32; off > 0; off >>= 1) v += __shfl_down(v, off, 64);
    return v;
}

// ---------------------------------------------------------------- k_prepw
// merged: [0,1600) cvtwq | [1600,4408) wknorm | [4408,7216) wbinv
//         [7216,7376) filt (thread-per-output) | [7376,7396) wgt
__global__ __launch_bounds__(256) void k_prepw(const float* __restrict__ l2v,
    const float* __restrict__ w1, const float* __restrict__ b1,
    const float* __restrict__ w2, const float* __restrict__ b2,
    const float* __restrict__ wq, const float* __restrict__ wk,
    const float* __restrict__ wb, const float* __restrict__ wt1,
    const float* __restrict__ bt1, const float* __restrict__ wt2,
    const float* __restrict__ bt2, const float* __restrict__ tb,
    const float* __restrict__ tl1, const float* __restrict__ tl2,
    ushort* __restrict__ filtb, float* __restrict__ wgt,
    unsigned* __restrict__ wqb_u, ushort* __restrict__ wknb,
    float* __restrict__ invb)
{
    int b = blockIdx.x;
    int tid = threadIdx.x, lane = tid & 63, wv = tid >> 6;
    __shared__ float red4[4];
    __shared__ float l2s[NSEM];
    __shared__ float hS[NSEM];
    __shared__ float fS[NDIM];
    __shared__ float h2[NSEMH];
    __shared__ float wl[NT];
    __shared__ float ssum;

    if (b < 1600) {
        size_t i = ((size_t)b * 256 + tid) * 8;
        const f32x4u a = *(const f32x4u*)(wq + i);
        const f32x4u c = *(const f32x4u*)(wq + i + 4);
        wqb_u[i / 2 + 0] = pkbf_(a[0], a[1]);
        wqb_u[i / 2 + 1] = pkbf_(a[2], a[3]);
        wqb_u[i / 2 + 2] = pkbf_(c[0], c[1]);
        wqb_u[i / 2 + 3] = pkbf_(c[2], c[3]);
        return;
    }
    if (b < 4408) {         // wknorm: r = t*351 + k
        int r = b - 1600;
        int t = r / NCLS, k = r - t * NCLS;
        const float* src = wk + (size_t)r * NDIM;
        float v0 = src[tid], v1 = src[tid + 256];
        bool h = tid < 128;
        float v2 = h ? src[tid + 512] : 0.f;
        float ss = v0 * v0 + v1 * v1 + v2 * v2;
        ss = waveReduceSum(ss);
        if (lane == 0) red4[wv] = ss;
        __syncthreads();
        float inv = invl2_(red4[0] + red4[1] + red4[2] + red4[3]);
        ushort* dst = wknb + ((size_t)t * 384 + k) * NDIM;
        dst[tid] = (ushort)bfr_(v0 * inv);
        dst[tid + 256] = (ushort)bfr_(v1 * inv);
        if (h) dst[tid + 512] = (ushort)bfr_(v2 * inv);
        return;
    }
    if (b < 7216) {         // wbinv: r = k*8 + t
        int r = b - 4408;
        const float* src = wb + (size_t)r * NDIM;
        float v0 = src[tid], v1 = src[tid + 256];
        float v2 = (tid < 128) ? src[tid + 512] : 0.f;
        float ss = v0 * v0 + v1 * v1 + v2 * v2;
        ss = waveReduceSum(ss);
        if (lane == 0) red4[wv] = ss;
        __syncthreads();
        if (tid == 0) invb[r] = invl2_(red4[0] + red4[1] + red4[2] + red4[3]);
        return;
    }
    if (b < 7376) {         // filt: one block per wt, thread-per-output
        int wt = b - 7216;
        int w = wt >> 3, t = wt & 7;
        for (int s = tid; s < NSEM; s += 256) l2s[s] = l2v[w * NSEM + s];
        __syncthreads();
        for (int d = tid; d < NSEM; d += 256) {
            const f32x4u* wr = (const f32x4u*)(w1 + ((size_t)t * NSEM + d) * NSEM);
            float a0 = 0.f, a1 = 0.f, a2 = 0.f, a3 = 0.f;
#pragma unroll 5
            for (int s4 = 0; s4 < 75; ++s4) {
                f32x4u v = wr[s4];
                a0 += v[0] * l2s[s4 * 4 + 0];
                a1 += v[1] * l2s[s4 * 4 + 1];
                a2 += v[2] * l2s[s4 * 4 + 2];
                a3 += v[3] * l2s[s4 * 4 + 3];
            }
            hS[d] = lreluf_((a0 + a1) + (a2 + a3) + b1[t * NSEM + d]);
        }
        __syncthreads();
        for (int c = tid; c < NDIM; c += 256) {
            const f32x4u* wr = (const f32x4u*)(w2 + ((size_t)t * NDIM + c) * NSEM);
            float a0 = 0.f, a1 = 0.f, a2 = 0.f, a3 = 0.f;
#pragma unroll 5
            for (int s4 = 0; s4 < 75; ++s4) {
                f32x4u v = wr[s4];
                a0 += v[0] * hS[s4 * 4 + 0];
                a1 += v[1] * hS[s4 * 4 + 1];
                a2 += v[2] * hS[s4 * 4 + 2];
                a3 += v[3] * hS[s4 * 4 + 3];
            }
            fS[c] = (a0 + a1) + (a2 + a3) + b2[t * NDIM + c];
        }
        __syncthreads();
        float ss = 0.f;
        for (int c = tid; c < NDIM; c += 256) ss += fS[c] * fS[c];
        ss = waveReduceSum(ss);
        if (lane == 0) red4[wv] = ss;
        __syncthreads();
        float inv = invl2_(red4[0] + red4[1] + red4[2] + red4[3]);
        for (int c = tid; c < NDIM; c += 256)
            filtb[(size_t)wt * NDIM + c] = (ushort)bfr_(fS[c] * inv);
        return;
    }
    {                       // wgt
        int w = b - 7376;
        if (tid < NSEMH) {
            float acc = 0.f;
            for (int s = 0; s < NSEM; ++s) acc += l2v[w * NSEM + s] * wt1[tid * NSEM + s];
            h2[tid] = lreluf_(acc + bt1[tid]);
        }
        __syncthreads();
        if (tid < NT) {
            float acc = 0.f;
            for (int d = 0; d < NSEMH; ++d) acc += h2[d] * wt2[tid * NSEMH + d];
            float wg = sigmoidf_(acc + bt2[tid]);
            wl[tid] = tl1[0] * tl1[0] * sigmoidf_(tb[tid]) + tl2[0] * tl2[0] * wg;
        }
        __syncthreads();
        if (tid == 0) { float s2 = 0.f; for (int t = 0; t < NT; ++t) s2 += wl[t]; ssum = s2; }
        __syncthreads();
        if (tid < NT) wgt[w * NT + tid] = wl[tid] / ssum;
    }
}

// ---------------------------------------------------------------- k_wbT : wbn^T bf16 [t][c 640][k 384pad]
__global__ __launch_bounds__(256) void k_wbT(const float* __restrict__ wb,
    const float* __restrict__ invb, unsigned* __restrict__ wbnT_u)
{
    int k0 = blockIdx.x * 64, c0 = blockIdx.y * 64, t = blockIdx.z;
    int tid = threadIdx.x;
    __shared__ float tile[64][65];
    __shared__ float invT[64];
    {
        int i = tid >> 2, q = tid & 3;
        int kg = min(k0 + i, NCLS - 1);
#pragma unroll
        for (int u = 0; u < 4; ++u) {
            int c = q * 16 + u * 4;
            f32x4u v = *(const f32x4u*)(wb + ((size_t)kg * NT + t) * NDIM + c0 + c);
            tile[i][c] = v[0]; tile[i][c + 1] = v[1]; tile[i][c + 2] = v[2]; tile[i][c + 3] = v[3];
        }
        if (tid < 64) {
            int kg2 = k0 + tid;
            invT[tid] = (kg2 < NCLS) ? invb[(size_t)kg2 * NT + t] : 0.f;
        }
    }
    __syncthreads();
    int cc = tid >> 2, qq = tid & 3;
    size_t rowo = (((size_t)t * NDIM + c0 + cc) * 384 + k0) / 2;
#pragma unroll
    for (int u = 0; u < 8; ++u) {
        int kl = qq * 16 + u * 2;
        float v0 = tile[kl][cc] * invT[kl];
        float v1 = tile[kl + 1][cc] * invT[kl + 1];
        wbnT_u[rowo + qq * 8 + u] = pkbf_(v0, v1);
    }
}

// ---------------------------------------------------------------- k_support2
__global__ __launch_bounds__(512) void k_support2(const float* __restrict__ spt,
    const ushort* __restrict__ filtb, float* __restrict__ sptn,
    ushort* __restrict__ xb)
{
    int w = blockIdx.x, s = blockIdx.y;
    int n = s * NWAY + w;
    int tid = threadIdx.x, lane = tid & 63, wv = tid >> 6;     // 8 waves
    int l15 = lane & 15, lh = lane >> 4;
    const float* base = spt + (size_t)n * NDIM * NXY;

    __shared__ unsigned actL[16 * 64];
    __shared__ float redT[8 * 8];
    __shared__ float invt[8];

    for (int i = tid; i < 16 * 64; i += 512) actL[i] = 0u;

    int xy = wv * 16 + l15;
    const float* colb = base + (xy < NXY ? xy : 0);
    const ushort* arow1 = filtb + (size_t)(w * NT + (l15 & 7)) * NDIM + lh * 8;
    f32x4 acc = {0.f, 0.f, 0.f, 0.f};
    float ssq = 0.f;
    for (int c0 = 0; c0 < NDIM; c0 += 32) {
        float v[8];
#pragma unroll
        for (int j = 0; j < 8; ++j) {
            v[j] = colb[(size_t)(c0 + lh * 8 + j) * NXY];
            ssq += v[j] * v[j];
        }
        union { unsigned u[4]; s16x8 x; } bf;
#pragma unroll
        for (int p = 0; p < 4; ++p) bf.u[p] = pkbf_(v[2 * p], v[2 * p + 1]);
        s16x8 af = *(const s16x8*)(arow1 + c0);
        acc = __builtin_amdgcn_mfma_f32_16x16x32_bf16(af, bf.x, acc, 0, 0, 0);
    }
    ssq += __shfl_xor(ssq, 16, 64);
    ssq += __shfl_xor(ssq, 32, 64);
    float inv = (xy < NXY) ? invl2_(ssq) : 0.f;
    __syncthreads();
#pragma unroll
    for (int r = 0; r < 4; ++r) {
        int row = lh * 4 + r;
        if (row < 8) {
            float a = sigmoidf_(acc[r] * inv) * inv;
            unsigned g = ((unsigned)(xy >> 3) ^ (unsigned)row) & 15u;
            *(ushort*)((char*)actL + (size_t)row * 256 + g * 16 + (xy & 7) * 2) = (ushort)bfr_(a);
        }
    }
    __syncthreads();

    f32x4 acc2[5];
#pragma unroll
    for (int f = 0; f < 5; ++f) acc2[f] = (f32x4){0.f, 0.f, 0.f, 0.f};
#pragma unroll
    for (int ks = 0; ks < 4; ++ks) {
        int xyb = ks * 32 + lh * 8;
        unsigned g = ((unsigned)(ks * 4 + lh) ^ (unsigned)l15) & 15u;
        s16x8 af = *(const s16x8*)&actL[l15 * 64 + g * 4];
#pragma unroll
        for (int f = 0; f < 5; ++f) {
            int c = (wv * 5 + f) * 16 + l15;
            const float* rp = base + (size_t)c * NXY;
            s16x8 bfv;
            if (ks == 3 && lh == 3) {
                union { unsigned u[4]; s16x8 v; } r;
                r.u[0] = pkbf_(rp[120], 0.f); r.u[1] = 0u; r.u[2] = 0u; r.u[3] = 0u;
                bfv = r.v;
            } else {
                bfv = cvt8_(rp + xyb);
            }
            acc2[f] = __builtin_amdgcn_mfma_f32_16x16x32_bf16(af, bfv, acc2[f], 0, 0, 0);
        }
    }
    {
        float pr[4] = {0.f, 0.f, 0.f, 0.f};
#pragma unroll
        for (int f = 0; f < 5; ++f)
#pragma unroll
            for (int r = 0; r < 4; ++r) pr[r] += acc2[f][r] * acc2[f][r];
#pragma unroll
        for (int r = 0; r < 4; ++r) {
#pragma unroll
            for (int off = 1; off < 16; off <<= 1) pr[r] += __shfl_xor(pr[r], off, 64);
        }
        if (l15 == 0 && lh < 2) {
#pragma unroll
            for (int r = 0; r < 4; ++r) redT[wv * 8 + lh * 4 + r] = pr[r];
        }
    }
    __syncthreads();
    if (tid < 8) {
        float s8 = 0.f;
#pragma unroll
        for (int w8 = 0; w8 < 8; ++w8) s8 += redT[w8 * 8 + tid];
        invt[tid] = invl2_(s8);
    }
    __syncthreads();
    if (lh < 2) {
#pragma unroll
        for (int f = 0; f < 5; ++f) {
            int c = (wv * 5 + f) * 16 + l15;
#pragma unroll
            for (int r = 0; r < 4; ++r) {
                int t = lh * 4 + r;
                float val = acc2[f][r] * invt[t];
                sptn[((size_t)n * NT + t) * NDIM + c] = val;
                xb[((size_t)t * 112 + n) * NDIM + c] = (ushort)bfr_(val);
            }
        }
    }
}

// ---------------------------------------------------------------- k_qatt (fused qe + att)
__global__ __launch_bounds__(512) void k_qatt(const ushort* __restrict__ xb,
    const ushort* __restrict__ wqb, const float* __restrict__ bq,
    const ushort* __restrict__ wknb, const ushort* __restrict__ wbnT,
    const float* __restrict__ sptn, const float* __restrict__ scale_att,
    const float* __restrict__ lamn, const float* __restrict__ lamb,
    float* __restrict__ comb)
{
    int t = blockIdx.x, mt = blockIdx.y, n0 = mt * 16;
    int tid = threadIdx.x, lane = tid & 63, wv = tid >> 6;     // 8 waves
    int l15 = lane & 15, lh = lane >> 4;
    __shared__ __align__(16) ushort qebL[16 * 640];            // swizzled (20 KB)
    __shared__ float scL[16 * 384];                            // 24 KB
    __shared__ __align__(16) unsigned attL[16 * 192];          // swizzled bf16 (12 KB)
    __shared__ float redQ[8 * 16];
    __shared__ float invR[16];

    // ---- phase Q: QE = X @ wq^T + bq, l2n rows ----
    f32x4 acc[5];
#pragma unroll
    for (int f = 0; f < 5; ++f) acc[f] = (f32x4){0.f, 0.f, 0.f, 0.f};
    float bqv[5];
#pragma unroll
    for (int f = 0; f < 5; ++f) bqv[f] = bq[t * NDIM + (wv * 5 + f) * 16 + l15];
    const ushort* arow = xb + ((size_t)t * 112 + n0 + l15) * NDIM + lh * 8;
    for (int k0 = 0; k0 < NDIM; k0 += 32) {
        s16x8 af = *(const s16x8*)(arow + k0);
#pragma unroll
        for (int f = 0; f < 5; ++f) {
            int d = (wv * 5 + f) * 16 + l15;
            s16x8 bv = *(const s16x8*)&wqb[((size_t)t * NDIM + d) * NDIM + k0 + lh * 8];
            acc[f] = __builtin_amdgcn_mfma_f32_16x16x32_bf16(af, bv, acc[f], 0, 0, 0);
        }
    }
    {
        float pr[4] = {0.f, 0.f, 0.f, 0.f};
#pragma unroll
        for (int f = 0; f < 5; ++f)
#pragma unroll
            for (int r = 0; r < 4; ++r) { float qv = acc[f][r] + bqv[f]; pr[r] += qv * qv; }
#pragma unroll
        for (int r = 0; r < 4; ++r) {
#pragma unroll
            for (int off = 1; off < 16; off <<= 1) pr[r] += __shfl_xor(pr[r], off, 64);
        }
        if (l15 == 0) {
#pragma unroll
            for (int r = 0; r < 4; ++r) redQ[wv * 16 + lh * 4 + r] = pr[r];
        }
    }
    __syncthreads();
    if (tid < 16) {
        float s = 0.f;
#pragma unroll
        for (int w8 = 0; w8 < 8; ++w8) s += redQ[w8 * 16 + tid];
        invR[tid] = invl2_(s);
    }
    __syncthreads();
#pragma unroll
    for (int f = 0; f < 5; ++f) {
        int d = (wv * 5 + f) * 16 + l15;
        unsigned g = (unsigned)(d >> 3);
        unsigned gh = g & ~15u, gl = g & 15u;
#pragma unroll
        for (int r = 0; r < 4; ++r) {
            int nn = lh * 4 + r;
            float qv = (acc[f][r] + bqv[f]) * invR[nn];
            unsigned gs = gh | (gl ^ (unsigned)nn);
            qebL[nn * 640 + gs * 8 + (d & 7)] = (ushort)bfr_(qv);
        }
    }
    __syncthreads();

    // ---- phase S: scores = scale * QE @ wkn^T ----
    f32x4 a3[3];
#pragma unroll
    for (int f = 0; f < 3; ++f) a3[f] = (f32x4){0.f, 0.f, 0.f, 0.f};
    for (int k0 = 0; k0 < NDIM; k0 += 32) {
        unsigned g = (unsigned)((k0 >> 3) + lh);
        unsigned gs = (g & ~15u) | ((g & 15u) ^ (unsigned)l15);
        s16x8 af = *(const s16x8*)&qebL[l15 * 640 + gs * 8];
#pragma unroll
        for (int f = 0; f < 3; ++f) {
            int kk = (wv * 3 + f) * 16 + l15;
            s16x8 bv = *(const s16x8*)&wknb[((size_t)t * 384 + kk) * NDIM + k0 + lh * 8];
            a3[f] = __builtin_amdgcn_mfma_f32_16x16x32_bf16(af, bv, a3[f], 0, 0, 0);
        }
    }
    float sat = scale_att[t];
#pragma unroll
    for (int f = 0; f < 3; ++f) {
        int kk = (wv * 3 + f) * 16 + l15;
#pragma unroll
        for (int r = 0; r < 4; ++r) scL[(lh * 4 + r) * 384 + kk] = sat * a3[f][r];
    }
    __syncthreads();
    {   // softmax: 16 rows x 32 threads
        int row = tid >> 5, li = tid & 31;
        float e[12]; float mx = -1e30f;
#pragma unroll
        for (int j = 0; j < 12; ++j) {
            int k = li + 32 * j;
            float v = (k < NCLS) ? scL[row * 384 + k] : -1e30f;
            e[j] = v; mx = fmaxf(mx, v);
        }
#pragma unroll
        for (int off = 1; off < 32; off <<= 1) mx = fmaxf(mx, __shfl_xor(mx, off, 64));
        float se = 0.f;
#pragma unroll
        for (int j = 0; j < 12; ++j) {
            int k = li + 32 * j;
            float ev = (k < NCLS) ? expf(e[j] - mx) : 0.f;
            e[j] = ev; se += ev;
        }
#pragma unroll
        for (int off = 1; off < 32; off <<= 1) se += __shfl_xor(se, off, 64);
        float is = 1.f / se;
#pragma unroll
        for (int j = 0; j < 12; ++j) scL[row * 384 + li + 32 * j] = e[j] * is;
    }
    __syncthreads();
    // pack att -> attL bf16 swizzled
    for (int idx = tid; idx < 3072; idx += 512) {
        int row = idx / 192, pp = idx - row * 192;
        int k2 = 2 * pp;
        unsigned g = (unsigned)(k2 >> 3);
        unsigned gs = (g & ~15u) | ((g & 15u) ^ (unsigned)row);
        attL[row * 192 + gs * 4 + ((k2 >> 1) & 3)] = pkbf_(scL[row * 384 + k2], scL[row * 384 + k2 + 1]);
    }
    __syncthreads();

    // ---- phase W: wtb = att @ wbnT ; comb epilogue ----
    f32x4 a4[5];
#pragma unroll
    for (int f = 0; f < 5; ++f) a4[f] = (f32x4){0.f, 0.f, 0.f, 0.f};
    const ushort* attp = (const ushort*)attL;
    for (int k0 = 0; k0 < 384; k0 += 32) {
        unsigned g = (unsigned)((k0 >> 3) + lh);
        unsigned gs = (g & ~15u) | ((g & 15u) ^ (unsigned)l15);
        s16x8 af = *(const s16x8*)&attp[l15 * 384 + gs * 8];
#pragma unroll
        for (int f = 0; f < 5; ++f) {
            int c = (wv * 5 + f) * 16 + l15;
            s16x8 bv = *(const s16x8*)&wbnT[((size_t)t * NDIM + c) * 384 + k0 + lh * 8];
            a4[f] = __builtin_amdgcn_mfma_f32_16x16x32_bf16(af, bv, a4[f], 0, 0, 0);
        }
    }
    float ln2 = lamn[t] * lamn[t], lb2 = lamb[t] * lamb[t];
#pragma unroll
    for (int f = 0; f < 5; ++f) {
        int c = (wv * 5 + f) * 16 + l15;
#pragma unroll
        for (int r = 0; r < 4; ++r) {
            int ng = n0 + lh * 4 + r;
            if (ng < 100) {
                size_t o = ((size_t)ng * NT + t) * NDIM + c;
                comb[o] = ln2 * sptn[o] + lb2 * a4[f][r];
            }
        }
    }
}

// ---------------------------------------------------------------- k_proto
__global__ __launch_bounds__(128) void k_proto(const float* __restrict__ comb,
    float* __restrict__ proto)
{
    int wt = blockIdx.x;
    int w = wt >> 3, t = wt & 7;
    int tid = threadIdx.x, lane = tid & 63, wv = tid >> 6;
    __shared__ float red[2];
    float mv[5]; float ss = 0.f;
#pragma unroll
    for (int m = 0; m < 5; ++m) {
        int c = tid + 128 * m;
        float a = 0.f;
#pragma unroll
        for (int s = 0; s < NSHOT; ++s)
            a += comb[(((size_t)(s * NWAY + w)) * NT + t) * NDIM + c];
        a *= 0.2f;
        mv[m] = a; ss += a * a;
    }
    ss = waveReduceSum(ss);
    if (lane == 0) red[wv] = ss;
    __syncthreads();
    float inv = invl2_(red[0] + red[1]);
#pragma unroll
    for (int m = 0; m < 5; ++m) proto[(size_t)wt * NDIM + tid + 128 * m] = mv[m] * inv;
}

// ---------------------------------------------------------------- k_qprep3
// grid (5, 500) per chunk: block (ct, ql) converts a 128-c chunk of query q0+ql
// to bf16 in BOTH layouts: qbT[ql][128 xy][640 c] and qb[ql][640 c][128 xy]
// (tail zero-padded); emits per-xy ssq partials ssqP[ql][5][128].
__global__ __launch_bounds__(512) void k_qprep3(const float* __restrict__ qry,
    ushort* __restrict__ qbT, ushort* __restrict__ qb, float* __restrict__ ssqP,
    int q0)
{
    int ct = blockIdx.x, ql = blockIdx.y;
    int q = q0 + ql;
    int tid = threadIdx.x;
    int xy = tid & 127, cl = tid >> 7;     // cl 0..3
    const float* base = qry + (size_t)q * NDIM * NXY + (size_t)ct * 128 * NXY;
    bool vx = xy < NXY;
    __shared__ ushort tile[128][130];
    __shared__ float ssq4[4][128];
    float ss = 0.f;
    ushort* qbrow = qb + ((size_t)ql * NDIM + ct * 128) * 128;
#pragma unroll 8
    for (int j = 0; j < 32; ++j) {
        int cloc = cl * 32 + j;
        float v = vx ? base[(size_t)cloc * NXY + xy] : 0.f;
        ss += v * v;
        ushort bv = (ushort)bfr_(v);
        tile[xy][cloc] = bv;
        qbrow[(size_t)cloc * 128 + xy] = bv;       // natural layout, coalesced over xy
    }
    ssq4[cl][xy] = ss;
    __syncthreads();
    unsigned* qT = (unsigned*)(qbT + (size_t)ql * 128 * NDIM) + ct * 64;
    for (int idx = tid; idx < 128 * 64; idx += 512) {
        int row = idx >> 6, p = idx & 63;
        qT[(size_t)row * 320 + p] = *(const unsigned*)&tile[row][2 * p];
    }
    if (tid < 128) {
        float s = ssq4[0][tid] + ssq4[1][tid] + ssq4[2][tid] + ssq4[3][tid];
        ssqP[((size_t)ql * 5 + ct) * 128 + tid] = s;
    }
}

// ---------------------------------------------------------------- k_query7 (fused act + pool + sim, 16 waves)
// One block per query (chunk-local ql). Phase 1: B = 16B qbT rows (2 waves per
// xy-group split 10 m-tiles). Phase 2: B = 16B qb rows; 16 waves (ns, a_).
__global__ __launch_bounds__(1024) void k_query7(
    const ushort* __restrict__ qbT, const ushort* __restrict__ qb,
    const float* __restrict__ ssqP, const ushort* __restrict__ filtb,
    const float* __restrict__ proto, const float* __restrict__ wgt,
    float* __restrict__ out, int q0)
{
    int ql = blockIdx.x;
    int q = q0 + ql;
    int tid = threadIdx.x, lane = tid & 63, wv = tid >> 6;     // 16 waves
    int l15 = lane & 15, lh = lane >> 4;
    __shared__ __align__(16) unsigned actL[160 * 64];          // 40 KB swizzled
    __shared__ float simacc[16 * NWT * 2];                     // 20 KB
    __shared__ float simF[NWT];
    __shared__ float invS[128];

    if (tid < 128) {
        const float* sp = ssqP + (size_t)ql * 640 + tid;
        float s = sp[0] + sp[128] + sp[256] + sp[384] + sp[512];
        invS[tid] = (tid < NXY) ? invl2_(s) : 0.f;
    }
    for (int i = tid; i < 16 * NWT * 2; i += 1024) simacc[i] = 0.f;
    __syncthreads();

    // ---------------- phase 1: act' ----------------
    int xyg = wv & 7, mh = wv >> 3;       // xy-group 0..7, m-half 0..1
    int xy = xyg * 16 + l15;
    f32x4 acc[5];
#pragma unroll
    for (int m = 0; m < 5; ++m) acc[m] = (f32x4){0.f, 0.f, 0.f, 0.f};
    const ushort* brow = qbT + ((size_t)ql * 128 + xy) * NDIM + lh * 8;
    for (int c0 = 0; c0 < NDIM; c0 += 32) {
        s16x8 bf = *(const s16x8*)(brow + c0);
#pragma unroll
        for (int mi = 0; mi < 5; ++mi) {
            int m = mh * 5 + mi;
            s16x8 af = *(const s16x8*)&filtb[(size_t)(m * 16 + l15) * NDIM + c0 + lh * 8];
            acc[mi] = __builtin_amdgcn_mfma_f32_16x16x32_bf16(af, bf, acc[mi], 0, 0, 0);
        }
    }
    {
        float inv = invS[xy];
        unsigned xg = (unsigned)(xy >> 3);
        unsigned xo = (unsigned)(xy & 7) * 2;
#pragma unroll
        for (int mi = 0; mi < 5; ++mi) {
#pragma unroll
            for (int r = 0; r < 4; ++r) {
                int row = (mh * 5 + mi) * 16 + lh * 4 + r;
                float a = sigmoidf_(acc[mi][r] * inv) * inv;   // act' (B in phase 2 is bf16 qry)
                unsigned g = xg ^ (unsigned)(row & 15);
                *(ushort*)((char*)actL + (size_t)row * 256 + g * 16 + xo) = (ushort)bfr_(a);
            }
        }
    }
    __syncthreads();

    // ---------------- phase 2: pool + sim ----------------
    int ns = wv & 3, a_ = wv >> 2;        // ns 0..3, a_ 0..3
    int cnt = (a_ < 2) ? 3 : 2;           // m = a_ + 4*i
    float dacc[3][4], sacc[3][4];
#pragma unroll
    for (int i = 0; i < 3; ++i)
#pragma unroll
        for (int r = 0; r < 4; ++r) { dacc[i][r] = 0.f; sacc[i][r] = 0.f; }

    const ushort* qbq = qb + (size_t)ql * NDIM * 128;
    for (int c0 = 0; c0 < NDIM; c0 += 64) {
        int cb = c0 + ns * 16 + l15;
        const ushort* rp = qbq + (size_t)cb * 128 + lh * 8;
        s16x8 bfv[4];
#pragma unroll
        for (int kk = 0; kk < 4; ++kk)
            bfv[kk] = *(const s16x8*)(rp + kk * 32);
#pragma unroll
        for (int i = 0; i < 3; ++i) {
            if (i < cnt) {
                int m = a_ + 4 * i;
                f32x4 c4 = (f32x4){0.f, 0.f, 0.f, 0.f};
#pragma unroll
                for (int kk = 0; kk < 4; ++kk) {
                    unsigned g = ((unsigned)(kk * 4 + lh) ^ (unsigned)l15) & 15u;
                    s16x8 af = *(const s16x8*)&actL[(m * 16 + l15) * 64 + g * 4];
                    c4 = __builtin_amdgcn_mfma_f32_16x16x32_bf16(af, bfv[kk], c4, 0, 0, 0);
                }
#pragma unroll
                for (int r = 0; r < 4; ++r) {
                    float p = proto[(size_t)(m * 16 + lh * 4 + r) * NDIM + cb];
                    dacc[i][r] += c4[r] * p;
                    sacc[i][r] += c4[r] * c4[r];
                }
            }
        }
    }
#pragma unroll
    for (int i = 0; i < 3; ++i) {
        if (i < cnt) {
#pragma unroll
            for (int r = 0; r < 4; ++r) {
                float d = dacc[i][r], s2 = sacc[i][r];
#pragma unroll
                for (int off = 1; off < 16; off <<= 1) {
                    d += __shfl_xor(d, off, 64);
                    s2 += __shfl_xor(s2, off, 64);
                }
                if (l15 == 0) {
                    int wt = (a_ + 4 * i) * 16 + lh * 4 + r;
                    simacc[(wv * NWT + wt) * 2 + 0] = d;
                    simacc[(wv * NWT + wt) * 2 + 1] = s2;
                }
            }
        }
    }
    __syncthreads();
    if (tid < NWT) {
        float d = 0.f, s2 = 0.f;
#pragma unroll
        for (int w16 = 0; w16 < 16; ++w16) {
            d += simacc[(w16 * NWT + tid) * 2 + 0];
            s2 += simacc[(w16 * NWT + tid) * 2 + 1];
        }
        simF[tid] = d * invl2_(s2);
    }
    __syncthreads();
    if (tid < NWAY) {
        float lg = 0.f;
#pragma unroll
        for (int t = 0; t < NT; ++t) lg += simF[tid * NT + t] * wgt[tid * NT + t];
        out[q * NWAY + tid] = 2.0f * lg;   // / TEMP
    }
}

extern "C" void kernel_launch(void* const* d_in, const int* in_sizes, int n_in,
                              void* d_out, int out_size, void* d_ws, size_t ws_size,
                              hipStream_t stream)
{
    const float* spt  = (const float*)d_in[0];
    const float* qry  = (const float*)d_in[1];
    const float* l2v  = (const float*)d_in[2];
    const float* w1   = (const float*)d_in[3];
    const float* b1   = (const float*)d_in[4];
    const float* w2   = (const float*)d_in[5];
    const float* b2   = (const float*)d_in[6];
    const float* wb   = (const float*)d_in[7];
    const float* wq   = (const float*)d_in[8];
    const float* bq   = (const float*)d_in[9];
    const float* wk   = (const float*)d_in[10];
    const float* sat  = (const float*)d_in[11];
    const float* lamn = (const float*)d_in[12];
    const float* lamb = (const float*)d_in[13];
    const float* wt1  = (const float*)d_in[14];
    const float* bt1  = (const float*)d_in[15];
    const float* wt2  = (const float*)d_in[16];
    const float* bt2  = (const float*)d_in[17];
    const float* tb   = (const float*)d_in[18];
    const float* tl1  = (const float*)d_in[19];
    const float* tl2  = (const float*)d_in[20];

    float* ws = (float*)d_ws;
    ushort*  filtb  = (ushort*)ws;                 // 51,200 f
    float*   wgt    = ws + 51200;                  // 160
    ushort*  wqb    = (ushort*)(ws + 51360);       // 1,638,400 f
    ushort*  wknb   = (ushort*)(ws + 1689760);     // 983,040 f
    ushort*  wbnT   = (ushort*)(ws + 2672800);     // 983,040 f
    float*   invb   = ws + 3655840;                // 2,816
    ushort*  xb     = (ushort*)(ws + 3658656);     // 286,720 f
    float*   sptn   = ws + 3945376;                // 512,000
    float*   combv  = ws + 4457376;                // 512,000
    float*   proto  = ws + 4969376;                // 102,400
    float*   ssqP   = ws + 5071776;                // 500*640 = 320,000
    ushort*  qbT    = (ushort*)(ws + 5391776);     // 500*128*640 bf16 = 20,480,000 f
    ushort*  qb     = (ushort*)(ws + 25871776);    // 500*640*128 bf16 = 20,480,000 f
    float*   outp   = (float*)d_out;               // total 46,351,776 f (~185 MB)

    hipLaunchKernelGGL(k_prepw,    dim3(7396),     dim3(256), 0, stream,
                       l2v, w1, b1, w2, b2, wq, wk, wb, wt1, bt1, wt2, bt2, tb, tl1, tl2,
                       filtb, wgt, (unsigned*)wqb, wknb, invb);
    hipLaunchKernelGGL(k_wbT,      dim3(6, 10, 8), dim3(256), 0, stream, wb, invb, (unsigned*)wbnT);
    hipLaunchKernelGGL(k_support2, dim3(20, 5),    dim3(512), 0, stream, spt, filtb, sptn, xb);
    hipLaunchKernelGGL(k_qatt,     dim3(8, 7),     dim3(512), 0, stream,
                       xb, wqb, bq, wknb, wbnT, sptn, sat, lamn, lamb, combv);
    hipLaunchKernelGGL(k_proto,    dim3(160),      dim3(128), 0, stream, combv, proto);
    for (int ch = 0; ch < 2; ++ch) {
        int q0 = ch * 500;
        hipLaunchKernelGGL(k_qprep3, dim3(5, 500), dim3(512), 0, stream, qry, qbT, qb, ssqP, q0);
        hipLaunchKernelGGL(k_query7, dim3(500),    dim3(1024), 0, stream,
                           qbT, qb, ssqP, filtb, proto, wgt, outp, q0);
    }
}

// Round 16
// 589.602 us; speedup vs baseline: 1.6898x; 1.6898x over previous
//
#include <hip/hip_runtime.h>
#include <hip/hip_bf16.h>

#define NWAY 20
#define NSHOT 5
#define NT 8
#define NDIM 640
#define NSEM 300
#define NSEMH 150
#define NCLS 351
#define NXY 121
#define NWT 160   // NWAY*NT, indexed wt = w*8 + t

typedef short s16x8 __attribute__((ext_vector_type(8)));
typedef float f32x4 __attribute__((ext_vector_type(4)));
typedef float f32x4u __attribute__((ext_vector_type(4), aligned(4)));

__device__ __forceinline__ float sigmoidf_(float x) { return 1.0f / (1.0f + expf(-x)); }
__device__ __forceinline__ float lreluf_(float x) { return x >= 0.0f ? x : 0.1f * x; }
__device__ __forceinline__ float invl2_(float ss) { return 1.0f / fmaxf(sqrtf(ss), 1e-12f); }

__device__ __forceinline__ unsigned bfr_(float f) {
    unsigned b = __float_as_uint(f);
    return (b + 0x7FFFu + ((b >> 16) & 1u)) >> 16;   // RNE to bf16
}
__device__ __forceinline__ unsigned pkbf_(float a, float b) { return bfr_(a) | (bfr_(b) << 16); }

__device__ __forceinline__ s16x8 cvt8_(const float* p) {
    f32x4u a = *(const f32x4u*)p;
    f32x4u b = *(const f32x4u*)(p + 4);
    union { unsigned u[4]; s16x8 v; } r;
    r.u[0] = pkbf_(a[0], a[1]); r.u[1] = pkbf_(a[2], a[3]);
    r.u[2] = pkbf_(b[0], b[1]); r.u[3] = pkbf_(b[2], b[3]);
    return r.v;
}

__device__ __forceinline__ float waveReduceSum(float v) {
#pragma unroll
    for (int off = 32; off > 0; off >>= 1) v += __shfl_down(v, off, 64);
    return v;
}

// ---------------------------------------------------------------- k_prepw
// merged: [0,1600) cvtwq | [1600,4408) wknorm | [4408,7216) wbinv
//         [7216,7376) filt (thread-per-output) | [7376,7396) wgt
__global__ __launch_bounds__(256) void k_prepw(const float* __restrict__ l2v,
    const float* __restrict__ w1, const float* __restrict__ b1,
    const float* __restrict__ w2, const float* __restrict__ b2,
    const float* __restrict__ wq, const float* __restrict__ wk,
    const float* __restrict__ wb, const float* __restrict__ wt1,
    const float* __restrict__ bt1, const float* __restrict__ wt2,
    const float* __restrict__ bt2, const float* __restrict__ tb,
    const float* __restrict__ tl1, const float* __restrict__ tl2,
    ushort* __restrict__ filtb, float* __restrict__ wgt,
    unsigned* __restrict__ wqb_u, ushort* __restrict__ wknb,
    float* __restrict__ invb)
{
    int b = blockIdx.x;
    int tid = threadIdx.x, lane = tid & 63, wv = tid >> 6;
    __shared__ float red4[4];
    __shared__ float l2s[NSEM];
    __shared__ float hS[NSEM];
    __shared__ float fS[NDIM];
    __shared__ float h2[NSEMH];
    __shared__ float wl[NT];
    __shared__ float ssum;

    if (b < 1600) {
        size_t i = ((size_t)b * 256 + tid) * 8;
        const f32x4u a = *(const f32x4u*)(wq + i);
        const f32x4u c = *(const f32x4u*)(wq + i + 4);
        wqb_u[i / 2 + 0] = pkbf_(a[0], a[1]);
        wqb_u[i / 2 + 1] = pkbf_(a[2], a[3]);
        wqb_u[i / 2 + 2] = pkbf_(c[0], c[1]);
        wqb_u[i / 2 + 3] = pkbf_(c[2], c[3]);
        return;
    }
    if (b < 4408) {         // wknorm: r = t*351 + k
        int r = b - 1600;
        int t = r / NCLS, k = r - t * NCLS;
        const float* src = wk + (size_t)r * NDIM;
        float v0 = src[tid], v1 = src[tid + 256];
        bool h = tid < 128;
        float v2 = h ? src[tid + 512] : 0.f;
        float ss = v0 * v0 + v1 * v1 + v2 * v2;
        ss = waveReduceSum(ss);
        if (lane == 0) red4[wv] = ss;
        __syncthreads();
        float inv = invl2_(red4[0] + red4[1] + red4[2] + red4[3]);
        ushort* dst = wknb + ((size_t)t * 384 + k) * NDIM;
        dst[tid] = (ushort)bfr_(v0 * inv);
        dst[tid + 256] = (ushort)bfr_(v1 * inv);
        if (h) dst[tid + 512] = (ushort)bfr_(v2 * inv);
        return;
    }
    if (b < 7216) {         // wbinv: r = k*8 + t
        int r = b - 4408;
        const float* src = wb + (size_t)r * NDIM;
        float v0 = src[tid], v1 = src[tid + 256];
        float v2 = (tid < 128) ? src[tid + 512] : 0.f;
        float ss = v0 * v0 + v1 * v1 + v2 * v2;
        ss = waveReduceSum(ss);
        if (lane == 0) red4[wv] = ss;
        __syncthreads();
        if (tid == 0) invb[r] = invl2_(red4[0] + red4[1] + red4[2] + red4[3]);
        return;
    }
    if (b < 7376) {         // filt: one block per wt, thread-per-output
        int wt = b - 7216;
        int w = wt >> 3, t = wt & 7;
        for (int s = tid; s < NSEM; s += 256) l2s[s] = l2v[w * NSEM + s];
        __syncthreads();
        for (int d = tid; d < NSEM; d += 256) {
            const f32x4u* wr = (const f32x4u*)(w1 + ((size_t)t * NSEM + d) * NSEM);
            float a0 = 0.f, a1 = 0.f, a2 = 0.f, a3 = 0.f;
#pragma unroll 5
            for (int s4 = 0; s4 < 75; ++s4) {
                f32x4u v = wr[s4];
                a0 += v[0] * l2s[s4 * 4 + 0];
                a1 += v[1] * l2s[s4 * 4 + 1];
                a2 += v[2] * l2s[s4 * 4 + 2];
                a3 += v[3] * l2s[s4 * 4 + 3];
            }
            hS[d] = lreluf_((a0 + a1) + (a2 + a3) + b1[t * NSEM + d]);
        }
        __syncthreads();
        for (int c = tid; c < NDIM; c += 256) {
            const f32x4u* wr = (const f32x4u*)(w2 + ((size_t)t * NDIM + c) * NSEM);
            float a0 = 0.f, a1 = 0.f, a2 = 0.f, a3 = 0.f;
#pragma unroll 5
            for (int s4 = 0; s4 < 75; ++s4) {
                f32x4u v = wr[s4];
                a0 += v[0] * hS[s4 * 4 + 0];
                a1 += v[1] * hS[s4 * 4 + 1];
                a2 += v[2] * hS[s4 * 4 + 2];
                a3 += v[3] * hS[s4 * 4 + 3];
            }
            fS[c] = (a0 + a1) + (a2 + a3) + b2[t * NDIM + c];
        }
        __syncthreads();
        float ss = 0.f;
        for (int c = tid; c < NDIM; c += 256) ss += fS[c] * fS[c];
        ss = waveReduceSum(ss);
        if (lane == 0) red4[wv] = ss;
        __syncthreads();
        float inv = invl2_(red4[0] + red4[1] + red4[2] + red4[3]);
        for (int c = tid; c < NDIM; c += 256)
            filtb[(size_t)wt * NDIM + c] = (ushort)bfr_(fS[c] * inv);
        return;
    }
    {                       // wgt
        int w = b - 7376;
        if (tid < NSEMH) {
            float acc = 0.f;
            for (int s = 0; s < NSEM; ++s) acc += l2v[w * NSEM + s] * wt1[tid * NSEM + s];
            h2[tid] = lreluf_(acc + bt1[tid]);
        }
        __syncthreads();
        if (tid < NT) {
            float acc = 0.f;
            for (int d = 0; d < NSEMH; ++d) acc += h2[d] * wt2[tid * NSEMH + d];
            float wg = sigmoidf_(acc + bt2[tid]);
            wl[tid] = tl1[0] * tl1[0] * sigmoidf_(tb[tid]) + tl2[0] * tl2[0] * wg;
        }
        __syncthreads();
        if (tid == 0) { float s2 = 0.f; for (int t = 0; t < NT; ++t) s2 += wl[t]; ssum = s2; }
        __syncthreads();
        if (tid < NT) wgt[w * NT + tid] = wl[tid] / ssum;
    }
}

// ---------------------------------------------------------------- k_wbT : wbn^T bf16 [t][c 640][k 384pad]
__global__ __launch_bounds__(256) void k_wbT(const float* __restrict__ wb,
    const float* __restrict__ invb, unsigned* __restrict__ wbnT_u)
{
    int k0 = blockIdx.x * 64, c0 = blockIdx.y * 64, t = blockIdx.z;
    int tid = threadIdx.x;
    __shared__ float tile[64][65];
    __shared__ float invT[64];
    {
        int i = tid >> 2, q = tid & 3;
        int kg = min(k0 + i, NCLS - 1);
#pragma unroll
        for (int u = 0; u < 4; ++u) {
            int c = q * 16 + u * 4;
            f32x4u v = *(const f32x4u*)(wb + ((size_t)kg * NT + t) * NDIM + c0 + c);
            tile[i][c] = v[0]; tile[i][c + 1] = v[1]; tile[i][c + 2] = v[2]; tile[i][c + 3] = v[3];
        }
        if (tid < 64) {
            int kg2 = k0 + tid;
            invT[tid] = (kg2 < NCLS) ? invb[(size_t)kg2 * NT + t] : 0.f;
        }
    }
    __syncthreads();
    int cc = tid >> 2, qq = tid & 3;
    size_t rowo = (((size_t)t * NDIM + c0 + cc) * 384 + k0) / 2;
#pragma unroll
    for (int u = 0; u < 8; ++u) {
        int kl = qq * 16 + u * 2;
        float v0 = tile[kl][cc] * invT[kl];
        float v1 = tile[kl + 1][cc] * invT[kl + 1];
        wbnT_u[rowo + qq * 8 + u] = pkbf_(v0, v1);
    }
}

// ---------------------------------------------------------------- k_support2
__global__ __launch_bounds__(512) void k_support2(const float* __restrict__ spt,
    const ushort* __restrict__ filtb, float* __restrict__ sptn,
    ushort* __restrict__ xb)
{
    int w = blockIdx.x, s = blockIdx.y;
    int n = s * NWAY + w;
    int tid = threadIdx.x, lane = tid & 63, wv = tid >> 6;     // 8 waves
    int l15 = lane & 15, lh = lane >> 4;
    const float* base = spt + (size_t)n * NDIM * NXY;

    __shared__ unsigned actL[16 * 64];
    __shared__ float redT[8 * 8];
    __shared__ float invt[8];

    for (int i = tid; i < 16 * 64; i += 512) actL[i] = 0u;

    int xy = wv * 16 + l15;
    const float* colb = base + (xy < NXY ? xy : 0);
    const ushort* arow1 = filtb + (size_t)(w * NT + (l15 & 7)) * NDIM + lh * 8;
    f32x4 acc = {0.f, 0.f, 0.f, 0.f};
    float ssq = 0.f;
    for (int c0 = 0; c0 < NDIM; c0 += 32) {
        float v[8];
#pragma unroll
        for (int j = 0; j < 8; ++j) {
            v[j] = colb[(size_t)(c0 + lh * 8 + j) * NXY];
            ssq += v[j] * v[j];
        }
        union { unsigned u[4]; s16x8 x; } bf;
#pragma unroll
        for (int p = 0; p < 4; ++p) bf.u[p] = pkbf_(v[2 * p], v[2 * p + 1]);
        s16x8 af = *(const s16x8*)(arow1 + c0);
        acc = __builtin_amdgcn_mfma_f32_16x16x32_bf16(af, bf.x, acc, 0, 0, 0);
    }
    ssq += __shfl_xor(ssq, 16, 64);
    ssq += __shfl_xor(ssq, 32, 64);
    float inv = (xy < NXY) ? invl2_(ssq) : 0.f;
    __syncthreads();
#pragma unroll
    for (int r = 0; r < 4; ++r) {
        int row = lh * 4 + r;
        if (row < 8) {
            float a = sigmoidf_(acc[r] * inv) * inv;
            unsigned g = ((unsigned)(xy >> 3) ^ (unsigned)row) & 15u;
            *(ushort*)((char*)actL + (size_t)row * 256 + g * 16 + (xy & 7) * 2) = (ushort)bfr_(a);
        }
    }
    __syncthreads();

    f32x4 acc2[5];
#pragma unroll
    for (int f = 0; f < 5; ++f) acc2[f] = (f32x4){0.f, 0.f, 0.f, 0.f};
#pragma unroll
    for (int ks = 0; ks < 4; ++ks) {
        int xyb = ks * 32 + lh * 8;
        unsigned g = ((unsigned)(ks * 4 + lh) ^ (unsigned)l15) & 15u;
        s16x8 af = *(const s16x8*)&actL[l15 * 64 + g * 4];
#pragma unroll
        for (int f = 0; f < 5; ++f) {
            int c = (wv * 5 + f) * 16 + l15;
            const float* rp = base + (size_t)c * NXY;
            s16x8 bfv;
            if (ks == 3 && lh == 3) {
                union { unsigned u[4]; s16x8 v; } r;
                r.u[0] = pkbf_(rp[120], 0.f); r.u[1] = 0u; r.u[2] = 0u; r.u[3] = 0u;
                bfv = r.v;
            } else {
                bfv = cvt8_(rp + xyb);
            }
            acc2[f] = __builtin_amdgcn_mfma_f32_16x16x32_bf16(af, bfv, acc2[f], 0, 0, 0);
        }
    }
    {
        float pr[4] = {0.f, 0.f, 0.f, 0.f};
#pragma unroll
        for (int f = 0; f < 5; ++f)
#pragma unroll
            for (int r = 0; r < 4; ++r) pr[r] += acc2[f][r] * acc2[f][r];
#pragma unroll
        for (int r = 0; r < 4; ++r) {
#pragma unroll
            for (int off = 1; off < 16; off <<= 1) pr[r] += __shfl_xor(pr[r], off, 64);
        }
        if (l15 == 0 && lh < 2) {
#pragma unroll
            for (int r = 0; r < 4; ++r) redT[wv * 8 + lh * 4 + r] = pr[r];
        }
    }
    __syncthreads();
    if (tid < 8) {
        float s8 = 0.f;
#pragma unroll
        for (int w8 = 0; w8 < 8; ++w8) s8 += redT[w8 * 8 + tid];
        invt[tid] = invl2_(s8);
    }
    __syncthreads();
    if (lh < 2) {
#pragma unroll
        for (int f = 0; f < 5; ++f) {
            int c = (wv * 5 + f) * 16 + l15;
#pragma unroll
            for (int r = 0; r < 4; ++r) {
                int t = lh * 4 + r;
                float val = acc2[f][r] * invt[t];
                sptn[((size_t)n * NT + t) * NDIM + c] = val;
                xb[((size_t)t * 112 + n) * NDIM + c] = (ushort)bfr_(val);
            }
        }
    }
}

// ---------------------------------------------------------------- k_qatt (fused qe + att)
__global__ __launch_bounds__(512) void k_qatt(const ushort* __restrict__ xb,
    const ushort* __restrict__ wqb, const float* __restrict__ bq,
    const ushort* __restrict__ wknb, const ushort* __restrict__ wbnT,
    const float* __restrict__ sptn, const float* __restrict__ scale_att,
    const float* __restrict__ lamn, const float* __restrict__ lamb,
    float* __restrict__ comb)
{
    int t = blockIdx.x, mt = blockIdx.y, n0 = mt * 16;
    int tid = threadIdx.x, lane = tid & 63, wv = tid >> 6;     // 8 waves
    int l15 = lane & 15, lh = lane >> 4;
    __shared__ __align__(16) ushort qebL[16 * 640];            // swizzled (20 KB)
    __shared__ float scL[16 * 384];                            // 24 KB
    __shared__ __align__(16) unsigned attL[16 * 192];          // swizzled bf16 (12 KB)
    __shared__ float redQ[8 * 16];
    __shared__ float invR[16];

    // ---- phase Q: QE = X @ wq^T + bq, l2n rows ----
    f32x4 acc[5];
#pragma unroll
    for (int f = 0; f < 5; ++f) acc[f] = (f32x4){0.f, 0.f, 0.f, 0.f};
    float bqv[5];
#pragma unroll
    for (int f = 0; f < 5; ++f) bqv[f] = bq[t * NDIM + (wv * 5 + f) * 16 + l15];
    const ushort* arow = xb + ((size_t)t * 112 + n0 + l15) * NDIM + lh * 8;
    for (int k0 = 0; k0 < NDIM; k0 += 32) {
        s16x8 af = *(const s16x8*)(arow + k0);
#pragma unroll
        for (int f = 0; f < 5; ++f) {
            int d = (wv * 5 + f) * 16 + l15;
            s16x8 bv = *(const s16x8*)&wqb[((size_t)t * NDIM + d) * NDIM + k0 + lh * 8];
            acc[f] = __builtin_amdgcn_mfma_f32_16x16x32_bf16(af, bv, acc[f], 0, 0, 0);
        }
    }
    {
        float pr[4] = {0.f, 0.f, 0.f, 0.f};
#pragma unroll
        for (int f = 0; f < 5; ++f)
#pragma unroll
            for (int r = 0; r < 4; ++r) { float qv = acc[f][r] + bqv[f]; pr[r] += qv * qv; }
#pragma unroll
        for (int r = 0; r < 4; ++r) {
#pragma unroll
            for (int off = 1; off < 16; off <<= 1) pr[r] += __shfl_xor(pr[r], off, 64);
        }
        if (l15 == 0) {
#pragma unroll
            for (int r = 0; r < 4; ++r) redQ[wv * 16 + lh * 4 + r] = pr[r];
        }
    }
    __syncthreads();
    if (tid < 16) {
        float s = 0.f;
#pragma unroll
        for (int w8 = 0; w8 < 8; ++w8) s += redQ[w8 * 16 + tid];
        invR[tid] = invl2_(s);
    }
    __syncthreads();
#pragma unroll
    for (int f = 0; f < 5; ++f) {
        int d = (wv * 5 + f) * 16 + l15;
        unsigned g = (unsigned)(d >> 3);
        unsigned gh = g & ~15u, gl = g & 15u;
#pragma unroll
        for (int r = 0; r < 4; ++r) {
            int nn = lh * 4 + r;
            float qv = (acc[f][r] + bqv[f]) * invR[nn];
            unsigned gs = gh | (gl ^ (unsigned)nn);
            qebL[nn * 640 + gs * 8 + (d & 7)] = (ushort)bfr_(qv);
        }
    }
    __syncthreads();

    // ---- phase S: scores = scale * QE @ wkn^T ----
    f32x4 a3[3];
#pragma unroll
    for (int f = 0; f < 3; ++f) a3[f] = (f32x4){0.f, 0.f, 0.f, 0.f};
    for (int k0 = 0; k0 < NDIM; k0 += 32) {
        unsigned g = (unsigned)((k0 >> 3) + lh);
        unsigned gs = (g & ~15u) | ((g & 15u) ^ (unsigned)l15);
        s16x8 af = *(const s16x8*)&qebL[l15 * 640 + gs * 8];
#pragma unroll
        for (int f = 0; f < 3; ++f) {
            int kk = (wv * 3 + f) * 16 + l15;
            s16x8 bv = *(const s16x8*)&wknb[((size_t)t * 384 + kk) * NDIM + k0 + lh * 8];
            a3[f] = __builtin_amdgcn_mfma_f32_16x16x32_bf16(af, bv, a3[f], 0, 0, 0);
        }
    }
    float sat = scale_att[t];
#pragma unroll
    for (int f = 0; f < 3; ++f) {
        int kk = (wv * 3 + f) * 16 + l15;
#pragma unroll
        for (int r = 0; r < 4; ++r) scL[(lh * 4 + r) * 384 + kk] = sat * a3[f][r];
    }
    __syncthreads();
    {   // softmax: 16 rows x 32 threads
        int row = tid >> 5, li = tid & 31;
        float e[12]; float mx = -1e30f;
#pragma unroll
        for (int j = 0; j < 12; ++j) {
            int k = li + 32 * j;
            float v = (k < NCLS) ? scL[row * 384 + k] : -1e30f;
            e[j] = v; mx = fmaxf(mx, v);
        }
#pragma unroll
        for (int off = 1; off < 32; off <<= 1) mx = fmaxf(mx, __shfl_xor(mx, off, 64));
        float se = 0.f;
#pragma unroll
        for (int j = 0; j < 12; ++j) {
            int k = li + 32 * j;
            float ev = (k < NCLS) ? expf(e[j] - mx) : 0.f;
            e[j] = ev; se += ev;
        }
#pragma unroll
        for (int off = 1; off < 32; off <<= 1) se += __shfl_xor(se, off, 64);
        float is = 1.f / se;
#pragma unroll
        for (int j = 0; j < 12; ++j) scL[row * 384 + li + 32 * j] = e[j] * is;
    }
    __syncthreads();
    // pack att -> attL bf16 swizzled
    for (int idx = tid; idx < 3072; idx += 512) {
        int row = idx / 192, pp = idx - row * 192;
        int k2 = 2 * pp;
        unsigned g = (unsigned)(k2 >> 3);
        unsigned gs = (g & ~15u) | ((g & 15u) ^ (unsigned)row);
        attL[row * 192 + gs * 4 + ((k2 >> 1) & 3)] = pkbf_(scL[row * 384 + k2], scL[row * 384 + k2 + 1]);
    }
    __syncthreads();

    // ---- phase W: wtb = att @ wbnT ; comb epilogue ----
    f32x4 a4[5];
#pragma unroll
    for (int f = 0; f < 5; ++f) a4[f] = (f32x4){0.f, 0.f, 0.f, 0.f};
    const ushort* attp = (const ushort*)attL;
    for (int k0 = 0; k0 < 384; k0 += 32) {
        unsigned g = (unsigned)((k0 >> 3) + lh);
        unsigned gs = (g & ~15u) | ((g & 15u) ^ (unsigned)l15);
        s16x8 af = *(const s16x8*)&attp[l15 * 384 + gs * 8];
#pragma unroll
        for (int f = 0; f < 5; ++f) {
            int c = (wv * 5 + f) * 16 + l15;
            s16x8 bv = *(const s16x8*)&wbnT[((size_t)t * NDIM + c) * 384 + k0 + lh * 8];
            a4[f] = __builtin_amdgcn_mfma_f32_16x16x32_bf16(af, bv, a4[f], 0, 0, 0);
        }
    }
    float ln2 = lamn[t] * lamn[t], lb2 = lamb[t] * lamb[t];
#pragma unroll
    for (int f = 0; f < 5; ++f) {
        int c = (wv * 5 + f) * 16 + l15;
#pragma unroll
        for (int r = 0; r < 4; ++r) {
            int ng = n0 + lh * 4 + r;
            if (ng < 100) {
                size_t o = ((size_t)ng * NT + t) * NDIM + c;
                comb[o] = ln2 * sptn[o] + lb2 * a4[f][r];
            }
        }
    }
}

// ---------------------------------------------------------------- k_proto
__global__ __launch_bounds__(128) void k_proto(const float* __restrict__ comb,
    float* __restrict__ proto)
{
    int wt = blockIdx.x;
    int w = wt >> 3, t = wt & 7;
    int tid = threadIdx.x, lane = tid & 63, wv = tid >> 6;
    __shared__ float red[2];
    float mv[5]; float ss = 0.f;
#pragma unroll
    for (int m = 0; m < 5; ++m) {
        int c = tid + 128 * m;
        float a = 0.f;
#pragma unroll
        for (int s = 0; s < NSHOT; ++s)
            a += comb[(((size_t)(s * NWAY + w)) * NT + t) * NDIM + c];
        a *= 0.2f;
        mv[m] = a; ss += a * a;
    }
    ss = waveReduceSum(ss);
    if (lane == 0) red[wv] = ss;
    __syncthreads();
    float inv = invl2_(red[0] + red[1]);
#pragma unroll
    for (int m = 0; m < 5; ++m) proto[(size_t)wt * NDIM + tid + 128 * m] = mv[m] * inv;
}

// ---------------------------------------------------------------- k_query3
// grid (2, 1000): hf = blockIdx.x (FASTEST -> both halves of a q adjacent in
// dispatch, qry slice stays L2/L3-hot), q = blockIdx.y.
// Phase 1: act' via direct-gather B (coalesced), swizzled LDS (80 rows).
// Phase 2: pool + proto-dot + ssq; block writes its own 10 logits.
__global__ __launch_bounds__(512, 4) void k_query3(const float* __restrict__ qry,
    const ushort* __restrict__ filtb, const float* __restrict__ proto,
    const float* __restrict__ wgt, float* __restrict__ out)
{
    int hf = blockIdx.x, q = blockIdx.y;
    int tid = threadIdx.x, lane = tid & 63, wv = tid >> 6;     // 8 waves
    int l15 = lane & 15, lh = lane >> 4;
    const float* qbase = qry + (size_t)q * NDIM * NXY;
    __shared__ __align__(16) unsigned actL[80 * 64];           // 20 KB swizzled
    __shared__ float simacc[8 * 80 * 2];                       // 5 KB
    __shared__ float simF[80];

    // ---------------- phase 1: act' (direct gather, no barriers) ----------------
    int xy = wv * 16 + l15;
    const float* colb = qbase + (xy < NXY ? xy : 0);
    f32x4 acc[5];
#pragma unroll
    for (int m = 0; m < 5; ++m) acc[m] = (f32x4){0.f, 0.f, 0.f, 0.f};
    float ssq = 0.f;
    for (int c0 = 0; c0 < NDIM; c0 += 32) {
        float v[8];
#pragma unroll
        for (int j = 0; j < 8; ++j) {
            v[j] = colb[(size_t)(c0 + lh * 8 + j) * NXY];
            ssq += v[j] * v[j];
        }
        union { unsigned u[4]; s16x8 x; } bf;
#pragma unroll
        for (int p = 0; p < 4; ++p) bf.u[p] = pkbf_(v[2 * p], v[2 * p + 1]);
#pragma unroll
        for (int m = 0; m < 5; ++m) {
            s16x8 af = *(const s16x8*)&filtb[(size_t)(hf * 80 + m * 16 + l15) * NDIM + c0 + lh * 8];
            acc[m] = __builtin_amdgcn_mfma_f32_16x16x32_bf16(af, bf.x, acc[m], 0, 0, 0);
        }
    }
    ssq += __shfl_xor(ssq, 16, 64);
    ssq += __shfl_xor(ssq, 32, 64);
    float inv = (xy < NXY) ? invl2_(ssq) : 0.f;
    for (int i = tid; i < 8 * 80 * 2; i += 512) simacc[i] = 0.f;
    {
        unsigned xg = (unsigned)(xy >> 3);
        unsigned xo = (unsigned)(xy & 7) * 2;
#pragma unroll
        for (int m = 0; m < 5; ++m) {
#pragma unroll
            for (int r = 0; r < 4; ++r) {
                int row = m * 16 + lh * 4 + r;    // 0..79 local
                float a = sigmoidf_(acc[m][r] * inv) * inv;
                unsigned g = (xg ^ (unsigned)row) & 15u;
                *(ushort*)((char*)actL + (size_t)row * 256 + g * 16 + xo) = (ushort)bfr_(a);
            }
        }
    }
    __syncthreads();

    // ---------------- phase 2: pool + sim ----------------
    int ns = wv & 3, a_ = wv >> 2;                // m = 3*a_ + i ; count 3 - a_
    float dacc[3][4], sacc[3][4];
#pragma unroll
    for (int i = 0; i < 3; ++i)
#pragma unroll
        for (int r = 0; r < 4; ++r) { dacc[i][r] = 0.f; sacc[i][r] = 0.f; }

    for (int c0 = 0; c0 < NDIM; c0 += 64) {
        int cb = c0 + ns * 16 + l15;
        const float* rp = qbase + (size_t)cb * NXY;
        s16x8 bfv[4];
#pragma unroll
        for (int kk = 0; kk < 4; ++kk) {
            if (kk == 3 && lh == 3) {
                union { unsigned u[4]; s16x8 v; } r;
                r.u[0] = pkbf_(rp[120], 0.f); r.u[1] = 0u; r.u[2] = 0u; r.u[3] = 0u;
                bfv[kk] = r.v;
            } else {
                bfv[kk] = cvt8_(rp + kk * 32 + lh * 8);
            }
        }
#pragma unroll
        for (int i = 0; i < 3; ++i) {
            if (i < 3 - a_) {
                int m = 3 * a_ + i;
                f32x4 c4 = (f32x4){0.f, 0.f, 0.f, 0.f};
#pragma unroll
                for (int kk = 0; kk < 4; ++kk) {
                    unsigned g = ((unsigned)(kk * 4 + lh) ^ (unsigned)l15) & 15u;
                    s16x8 af = *(const s16x8*)&actL[(m * 16 + l15) * 64 + g * 4];
                    c4 = __builtin_amdgcn_mfma_f32_16x16x32_bf16(af, bfv[kk], c4, 0, 0, 0);
                }
#pragma unroll
                for (int r = 0; r < 4; ++r) {
                    float p = proto[(size_t)(hf * 80 + m * 16 + lh * 4 + r) * NDIM + cb];
                    dacc[i][r] += c4[r] * p;
                    sacc[i][r] += c4[r] * c4[r];
                }
            }
        }
    }
#pragma unroll
    for (int i = 0; i < 3; ++i) {
        if (i < 3 - a_) {
#pragma unroll
            for (int r = 0; r < 4; ++r) {
                float d = dacc[i][r], s2 = sacc[i][r];
#pragma unroll
                for (int off = 1; off < 16; off <<= 1) {
                    d += __shfl_xor(d, off, 64);
                    s2 += __shfl_xor(s2, off, 64);
                }
                if (l15 == 0) {
                    int wtl = (3 * a_ + i) * 16 + lh * 4 + r;
                    simacc[(wv * 80 + wtl) * 2 + 0] = d;
                    simacc[(wv * 80 + wtl) * 2 + 1] = s2;
                }
            }
        }
    }
    __syncthreads();
    if (tid < 80) {
        float d = 0.f, s2 = 0.f;
#pragma unroll
        for (int w8 = 0; w8 < 8; ++w8) {
            d += simacc[(w8 * 80 + tid) * 2 + 0];
            s2 += simacc[(w8 * 80 + tid) * 2 + 1];
        }
        simF[tid] = d * invl2_(s2);
    }
    __syncthreads();
    if (tid < 10) {
        int w = hf * 10 + tid;
        float lg = 0.f;
#pragma unroll
        for (int t = 0; t < NT; ++t) lg += simF[tid * NT + t] * wgt[w * NT + t];
        out[q * NWAY + w] = 2.0f * lg;   // / TEMP
    }
}

extern "C" void kernel_launch(void* const* d_in, const int* in_sizes, int n_in,
                              void* d_out, int out_size, void* d_ws, size_t ws_size,
                              hipStream_t stream)
{
    const float* spt  = (const float*)d_in[0];
    const float* qry  = (const float*)d_in[1];
    const float* l2v  = (const float*)d_in[2];
    const float* w1   = (const float*)d_in[3];
    const float* b1   = (const float*)d_in[4];
    const float* w2   = (const float*)d_in[5];
    const float* b2   = (const float*)d_in[6];
    const float* wb   = (const float*)d_in[7];
    const float* wq   = (const float*)d_in[8];
    const float* bq   = (const float*)d_in[9];
    const float* wk   = (const float*)d_in[10];
    const float* sat  = (const float*)d_in[11];
    const float* lamn = (const float*)d_in[12];
    const float* lamb = (const float*)d_in[13];
    const float* wt1  = (const float*)d_in[14];
    const float* bt1  = (const float*)d_in[15];
    const float* wt2  = (const float*)d_in[16];
    const float* bt2  = (const float*)d_in[17];
    const float* tb   = (const float*)d_in[18];
    const float* tl1  = (const float*)d_in[19];
    const float* tl2  = (const float*)d_in[20];

    float* ws = (float*)d_ws;
    ushort*  filtb  = (ushort*)ws;                 // 51,200 f
    float*   wgt    = ws + 51200;                  // 160
    ushort*  wqb    = (ushort*)(ws + 51360);       // 1,638,400 f
    ushort*  wknb   = (ushort*)(ws + 1689760);     // 983,040 f
    ushort*  wbnT   = (ushort*)(ws + 2672800);     // 983,040 f
    float*   invb   = ws + 3655840;                // 2,816
    ushort*  xb     = (ushort*)(ws + 3658656);     // 286,720 f
    float*   sptn   = ws + 3945376;                // 512,000
    float*   combv  = ws + 4457376;                // 512,000
    float*   proto  = ws + 4969376;                // 102,400
    float*   outp   = (float*)d_out;               // ws total ~5.07M floats (~20 MB)

    hipLaunchKernelGGL(k_prepw,    dim3(7396),     dim3(256), 0, stream,
                       l2v, w1, b1, w2, b2, wq, wk, wb, wt1, bt1, wt2, bt2, tb, tl1, tl2,
                       filtb, wgt, (unsigned*)wqb, wknb, invb);
    hipLaunchKernelGGL(k_wbT,      dim3(6, 10, 8), dim3(256), 0, stream, wb, invb, (unsigned*)wbnT);
    hipLaunchKernelGGL(k_support2, dim3(20, 5),    dim3(512), 0, stream, spt, filtb, sptn, xb);
    hipLaunchKernelGGL(k_qatt,     dim3(8, 7),     dim3(512), 0, stream,
                       xb, wqb, bq, wknb, wbnT, sptn, sat, lamn, lamb, combv);
    hipLaunchKernelGGL(k_proto,    dim3(160),      dim3(128), 0, stream, combv, proto);
    hipLaunchKernelGGL(k_query3,   dim3(2, 1000),  dim3(512), 0, stream,
                       qry, filtb, proto, wgt, outp);
}

// Round 17
// 549.454 us; speedup vs baseline: 1.8133x; 1.0731x over previous
//
#include <hip/hip_runtime.h>
#include <hip/hip_bf16.h>

#define NWAY 20
#define NSHOT 5
#define NT 8
#define NDIM 640
#define NSEM 300
#define NSEMH 150
#define NCLS 351
#define NXY 121
#define NWT 160   // NWAY*NT, indexed wt = w*8 + t

typedef short s16x8 __attribute__((ext_vector_type(8)));
typedef float f32x4 __attribute__((ext_vector_type(4)));
typedef float f32x4u __attribute__((ext_vector_type(4), aligned(4)));

__device__ __forceinline__ float sigmoidf_(float x) { return 1.0f / (1.0f + expf(-x)); }
__device__ __forceinline__ float lreluf_(float x) { return x >= 0.0f ? x : 0.1f * x; }
__device__ __forceinline__ float invl2_(float ss) { return 1.0f / fmaxf(sqrtf(ss), 1e-12f); }

__device__ __forceinline__ unsigned bfr_(float f) {
    unsigned b = __float_as_uint(f);
    return (b + 0x7FFFu + ((b >> 16) & 1u)) >> 16;   // RNE to bf16
}
__device__ __forceinline__ unsigned pkbf_(float a, float b) { return bfr_(a) | (bfr_(b) << 16); }

__device__ __forceinline__ s16x8 cvt8_(const float* p) {
    f32x4u a = *(const f32x4u*)p;
    f32x4u b = *(const f32x4u*)(p + 4);
    union { unsigned u[4]; s16x8 v; } r;
    r.u[0] = pkbf_(a[0], a[1]); r.u[1] = pkbf_(a[2], a[3]);
    r.u[2] = pkbf_(b[0], b[1]); r.u[3] = pkbf_(b[2], b[3]);
    return r.v;
}

__device__ __forceinline__ float waveReduceSum(float v) {
#pragma unroll
    for (int off = 32; off > 0; off >>= 1) v += __shfl_down(v, off, 64);
    return v;
}

// ---------------------------------------------------------------- k_prepw
// merged: [0,1600) cvtwq | [1600,4408) wknorm | [4408,7216) wbinv
//         [7216,7376) filt (thread-per-output) | [7376,7396) wgt
__global__ __launch_bounds__(256) void k_prepw(const float* __restrict__ l2v,
    const float* __restrict__ w1, const float* __restrict__ b1,
    const float* __restrict__ w2, const float* __restrict__ b2,
    const float* __restrict__ wq, const float* __restrict__ wk,
    const float* __restrict__ wb, const float* __restrict__ wt1,
    const float* __restrict__ bt1, const float* __restrict__ wt2,
    const float* __restrict__ bt2, const float* __restrict__ tb,
    const float* __restrict__ tl1, const float* __restrict__ tl2,
    ushort* __restrict__ filtb, float* __restrict__ wgt,
    unsigned* __restrict__ wqb_u, ushort* __restrict__ wknb,
    float* __restrict__ invb)
{
    int b = blockIdx.x;
    int tid = threadIdx.x, lane = tid & 63, wv = tid >> 6;
    __shared__ float red4[4];
    __shared__ float l2s[NSEM];
    __shared__ float hS[NSEM];
    __shared__ float fS[NDIM];
    __shared__ float h2[NSEMH];
    __shared__ float wl[NT];
    __shared__ float ssum;

    if (b < 1600) {
        size_t i = ((size_t)b * 256 + tid) * 8;
        const f32x4u a = *(const f32x4u*)(wq + i);
        const f32x4u c = *(const f32x4u*)(wq + i + 4);
        wqb_u[i / 2 + 0] = pkbf_(a[0], a[1]);
        wqb_u[i / 2 + 1] = pkbf_(a[2], a[3]);
        wqb_u[i / 2 + 2] = pkbf_(c[0], c[1]);
        wqb_u[i / 2 + 3] = pkbf_(c[2], c[3]);
        return;
    }
    if (b < 4408) {         // wknorm: r = t*351 + k
        int r = b - 1600;
        int t = r / NCLS, k = r - t * NCLS;
        const float* src = wk + (size_t)r * NDIM;
        float v0 = src[tid], v1 = src[tid + 256];
        bool h = tid < 128;
        float v2 = h ? src[tid + 512] : 0.f;
        float ss = v0 * v0 + v1 * v1 + v2 * v2;
        ss = waveReduceSum(ss);
        if (lane == 0) red4[wv] = ss;
        __syncthreads();
        float inv = invl2_(red4[0] + red4[1] + red4[2] + red4[3]);
        ushort* dst = wknb + ((size_t)t * 384 + k) * NDIM;
        dst[tid] = (ushort)bfr_(v0 * inv);
        dst[tid + 256] = (ushort)bfr_(v1 * inv);
        if (h) dst[tid + 512] = (ushort)bfr_(v2 * inv);
        return;
    }
    if (b < 7216) {         // wbinv: r = k*8 + t
        int r = b - 4408;
        const float* src = wb + (size_t)r * NDIM;
        float v0 = src[tid], v1 = src[tid + 256];
        float v2 = (tid < 128) ? src[tid + 512] : 0.f;
        float ss = v0 * v0 + v1 * v1 + v2 * v2;
        ss = waveReduceSum(ss);
        if (lane == 0) red4[wv] = ss;
        __syncthreads();
        if (tid == 0) invb[r] = invl2_(red4[0] + red4[1] + red4[2] + red4[3]);
        return;
    }
    if (b < 7376) {         // filt: one block per wt, thread-per-output
        int wt = b - 7216;
        int w = wt >> 3, t = wt & 7;
        for (int s = tid; s < NSEM; s += 256) l2s[s] = l2v[w * NSEM + s];
        __syncthreads();
        for (int d = tid; d < NSEM; d += 256) {
            const f32x4u* wr = (const f32x4u*)(w1 + ((size_t)t * NSEM + d) * NSEM);
            float a0 = 0.f, a1 = 0.f, a2 = 0.f, a3 = 0.f;
#pragma unroll 5
            for (int s4 = 0; s4 < 75; ++s4) {
                f32x4u v = wr[s4];
                a0 += v[0] * l2s[s4 * 4 + 0];
                a1 += v[1] * l2s[s4 * 4 + 1];
                a2 += v[2] * l2s[s4 * 4 + 2];
                a3 += v[3] * l2s[s4 * 4 + 3];
            }
            hS[d] = lreluf_((a0 + a1) + (a2 + a3) + b1[t * NSEM + d]);
        }
        __syncthreads();
        for (int c = tid; c < NDIM; c += 256) {
            const f32x4u* wr = (const f32x4u*)(w2 + ((size_t)t * NDIM + c) * NSEM);
            float a0 = 0.f, a1 = 0.f, a2 = 0.f, a3 = 0.f;
#pragma unroll 5
            for (int s4 = 0; s4 < 75; ++s4) {
                f32x4u v = wr[s4];
                a0 += v[0] * hS[s4 * 4 + 0];
                a1 += v[1] * hS[s4 * 4 + 1];
                a2 += v[2] * hS[s4 * 4 + 2];
                a3 += v[3] * hS[s4 * 4 + 3];
            }
            fS[c] = (a0 + a1) + (a2 + a3) + b2[t * NDIM + c];
        }
        __syncthreads();
        float ss = 0.f;
        for (int c = tid; c < NDIM; c += 256) ss += fS[c] * fS[c];
        ss = waveReduceSum(ss);
        if (lane == 0) red4[wv] = ss;
        __syncthreads();
        float inv = invl2_(red4[0] + red4[1] + red4[2] + red4[3]);
        for (int c = tid; c < NDIM; c += 256)
            filtb[(size_t)wt * NDIM + c] = (ushort)bfr_(fS[c] * inv);
        return;
    }
    {                       // wgt
        int w = b - 7376;
        if (tid < NSEMH) {
            float acc = 0.f;
            for (int s = 0; s < NSEM; ++s) acc += l2v[w * NSEM + s] * wt1[tid * NSEM + s];
            h2[tid] = lreluf_(acc + bt1[tid]);
        }
        __syncthreads();
        if (tid < NT) {
            float acc = 0.f;
            for (int d = 0; d < NSEMH; ++d) acc += h2[d] * wt2[tid * NSEMH + d];
            float wg = sigmoidf_(acc + bt2[tid]);
            wl[tid] = tl1[0] * tl1[0] * sigmoidf_(tb[tid]) + tl2[0] * tl2[0] * wg;
        }
        __syncthreads();
        if (tid == 0) { float s2 = 0.f; for (int t = 0; t < NT; ++t) s2 += wl[t]; ssum = s2; }
        __syncthreads();
        if (tid < NT) wgt[w * NT + tid] = wl[tid] / ssum;
    }
}

// ---------------------------------------------------------------- k_wbT : wbn^T bf16 [t][c 640][k 384pad]
__global__ __launch_bounds__(256) void k_wbT(const float* __restrict__ wb,
    const float* __restrict__ invb, unsigned* __restrict__ wbnT_u)
{
    int k0 = blockIdx.x * 64, c0 = blockIdx.y * 64, t = blockIdx.z;
    int tid = threadIdx.x;
    __shared__ float tile[64][65];
    __shared__ float invT[64];
    {
        int i = tid >> 2, q = tid & 3;
        int kg = min(k0 + i, NCLS - 1);
#pragma unroll
        for (int u = 0; u < 4; ++u) {
            int c = q * 16 + u * 4;
            f32x4u v = *(const f32x4u*)(wb + ((size_t)kg * NT + t) * NDIM + c0 + c);
            tile[i][c] = v[0]; tile[i][c + 1] = v[1]; tile[i][c + 2] = v[2]; tile[i][c + 3] = v[3];
        }
        if (tid < 64) {
            int kg2 = k0 + tid;
            invT[tid] = (kg2 < NCLS) ? invb[(size_t)kg2 * NT + t] : 0.f;
        }
    }
    __syncthreads();
    int cc = tid >> 2, qq = tid & 3;
    size_t rowo = (((size_t)t * NDIM + c0 + cc) * 384 + k0) / 2;
#pragma unroll
    for (int u = 0; u < 8; ++u) {
        int kl = qq * 16 + u * 2;
        float v0 = tile[kl][cc] * invT[kl];
        float v1 = tile[kl + 1][cc] * invT[kl + 1];
        wbnT_u[rowo + qq * 8 + u] = pkbf_(v0, v1);
    }
}

// ---------------------------------------------------------------- k_support2
__global__ __launch_bounds__(512) void k_support2(const float* __restrict__ spt,
    const ushort* __restrict__ filtb, float* __restrict__ sptn,
    ushort* __restrict__ xb)
{
    int w = blockIdx.x, s = blockIdx.y;
    int n = s * NWAY + w;
    int tid = threadIdx.x, lane = tid & 63, wv = tid >> 6;     // 8 waves
    int l15 = lane & 15, lh = lane >> 4;
    const float* base = spt + (size_t)n * NDIM * NXY;

    __shared__ unsigned actL[16 * 64];
    __shared__ float redT[8 * 8];
    __shared__ float invt[8];

    for (int i = tid; i < 16 * 64; i += 512) actL[i] = 0u;

    int xy = wv * 16 + l15;
    const float* colb = base + (xy < NXY ? xy : 0);
    const ushort* arow1 = filtb + (size_t)(w * NT + (l15 & 7)) * NDIM + lh * 8;
    f32x4 acc = {0.f, 0.f, 0.f, 0.f};
    float ssq = 0.f;
    for (int c0 = 0; c0 < NDIM; c0 += 32) {
        float v[8];
#pragma unroll
        for (int j = 0; j < 8; ++j) {
            v[j] = colb[(size_t)(c0 + lh * 8 + j) * NXY];
            ssq += v[j] * v[j];
        }
        union { unsigned u[4]; s16x8 x; } bf;
#pragma unroll
        for (int p = 0; p < 4; ++p) bf.u[p] = pkbf_(v[2 * p], v[2 * p + 1]);
        s16x8 af = *(const s16x8*)(arow1 + c0);
        acc = __builtin_amdgcn_mfma_f32_16x16x32_bf16(af, bf.x, acc, 0, 0, 0);
    }
    ssq += __shfl_xor(ssq, 16, 64);
    ssq += __shfl_xor(ssq, 32, 64);
    float inv = (xy < NXY) ? invl2_(ssq) : 0.f;
    __syncthreads();
#pragma unroll
    for (int r = 0; r < 4; ++r) {
        int row = lh * 4 + r;
        if (row < 8) {
            float a = sigmoidf_(acc[r] * inv) * inv;
            unsigned g = ((unsigned)(xy >> 3) ^ (unsigned)row) & 15u;
            *(ushort*)((char*)actL + (size_t)row * 256 + g * 16 + (xy & 7) * 2) = (ushort)bfr_(a);
        }
    }
    __syncthreads();

    f32x4 acc2[5];
#pragma unroll
    for (int f = 0; f < 5; ++f) acc2[f] = (f32x4){0.f, 0.f, 0.f, 0.f};
#pragma unroll
    for (int ks = 0; ks < 4; ++ks) {
        int xyb = ks * 32 + lh * 8;
        unsigned g = ((unsigned)(ks * 4 + lh) ^ (unsigned)l15) & 15u;
        s16x8 af = *(const s16x8*)&actL[l15 * 64 + g * 4];
#pragma unroll
        for (int f = 0; f < 5; ++f) {
            int c = (wv * 5 + f) * 16 + l15;
            const float* rp = base + (size_t)c * NXY;
            s16x8 bfv;
            if (ks == 3 && lh == 3) {
                union { unsigned u[4]; s16x8 v; } r;
                r.u[0] = pkbf_(rp[120], 0.f); r.u[1] = 0u; r.u[2] = 0u; r.u[3] = 0u;
                bfv = r.v;
            } else {
                bfv = cvt8_(rp + xyb);
            }
            acc2[f] = __builtin_amdgcn_mfma_f32_16x16x32_bf16(af, bfv, acc2[f], 0, 0, 0);
        }
    }
    {
        float pr[4] = {0.f, 0.f, 0.f, 0.f};
#pragma unroll
        for (int f = 0; f < 5; ++f)
#pragma unroll
            for (int r = 0; r < 4; ++r) pr[r] += acc2[f][r] * acc2[f][r];
#pragma unroll
        for (int r = 0; r < 4; ++r) {
#pragma unroll
            for (int off = 1; off < 16; off <<= 1) pr[r] += __shfl_xor(pr[r], off, 64);
        }
        if (l15 == 0 && lh < 2) {
#pragma unroll
            for (int r = 0; r < 4; ++r) redT[wv * 8 + lh * 4 + r] = pr[r];
        }
    }
    __syncthreads();
    if (tid < 8) {
        float s8 = 0.f;
#pragma unroll
        for (int w8 = 0; w8 < 8; ++w8) s8 += redT[w8 * 8 + tid];
        invt[tid] = invl2_(s8);
    }
    __syncthreads();
    if (lh < 2) {
#pragma unroll
        for (int f = 0; f < 5; ++f) {
            int c = (wv * 5 + f) * 16 + l15;
#pragma unroll
            for (int r = 0; r < 4; ++r) {
                int t = lh * 4 + r;
                float val = acc2[f][r] * invt[t];
                sptn[((size_t)n * NT + t) * NDIM + c] = val;
                xb[((size_t)t * 112 + n) * NDIM + c] = (ushort)bfr_(val);
            }
        }
    }
}

// ---------------------------------------------------------------- k_qatt (fused qe + att)
__global__ __launch_bounds__(512) void k_qatt(const ushort* __restrict__ xb,
    const ushort* __restrict__ wqb, const float* __restrict__ bq,
    const ushort* __restrict__ wknb, const ushort* __restrict__ wbnT,
    const float* __restrict__ sptn, const float* __restrict__ scale_att,
    const float* __restrict__ lamn, const float* __restrict__ lamb,
    float* __restrict__ comb)
{
    int t = blockIdx.x, mt = blockIdx.y, n0 = mt * 16;
    int tid = threadIdx.x, lane = tid & 63, wv = tid >> 6;     // 8 waves
    int l15 = lane & 15, lh = lane >> 4;
    __shared__ __align__(16) ushort qebL[16 * 640];            // swizzled (20 KB)
    __shared__ float scL[16 * 384];                            // 24 KB
    __shared__ __align__(16) unsigned attL[16 * 192];          // swizzled bf16 (12 KB)
    __shared__ float redQ[8 * 16];
    __shared__ float invR[16];

    // ---- phase Q: QE = X @ wq^T + bq, l2n rows ----
    f32x4 acc[5];
#pragma unroll
    for (int f = 0; f < 5; ++f) acc[f] = (f32x4){0.f, 0.f, 0.f, 0.f};
    float bqv[5];
#pragma unroll
    for (int f = 0; f < 5; ++f) bqv[f] = bq[t * NDIM + (wv * 5 + f) * 16 + l15];
    const ushort* arow = xb + ((size_t)t * 112 + n0 + l15) * NDIM + lh * 8;
    for (int k0 = 0; k0 < NDIM; k0 += 32) {
        s16x8 af = *(const s16x8*)(arow + k0);
#pragma unroll
        for (int f = 0; f < 5; ++f) {
            int d = (wv * 5 + f) * 16 + l15;
            s16x8 bv = *(const s16x8*)&wqb[((size_t)t * NDIM + d) * NDIM + k0 + lh * 8];
            acc[f] = __builtin_amdgcn_mfma_f32_16x16x32_bf16(af, bv, acc[f], 0, 0, 0);
        }
    }
    {
        float pr[4] = {0.f, 0.f, 0.f, 0.f};
#pragma unroll
        for (int f = 0; f < 5; ++f)
#pragma unroll
            for (int r = 0; r < 4; ++r) { float qv = acc[f][r] + bqv[f]; pr[r] += qv * qv; }
#pragma unroll
        for (int r = 0; r < 4; ++r) {
#pragma unroll
            for (int off = 1; off < 16; off <<= 1) pr[r] += __shfl_xor(pr[r], off, 64);
        }
        if (l15 == 0) {
#pragma unroll
            for (int r = 0; r < 4; ++r) redQ[wv * 16 + lh * 4 + r] = pr[r];
        }
    }
    __syncthreads();
    if (tid < 16) {
        float s = 0.f;
#pragma unroll
        for (int w8 = 0; w8 < 8; ++w8) s += redQ[w8 * 16 + tid];
        invR[tid] = invl2_(s);
    }
    __syncthreads();
#pragma unroll
    for (int f = 0; f < 5; ++f) {
        int d = (wv * 5 + f) * 16 + l15;
        unsigned g = (unsigned)(d >> 3);
        unsigned gh = g & ~15u, gl = g & 15u;
#pragma unroll
        for (int r = 0; r < 4; ++r) {
            int nn = lh * 4 + r;
            float qv = (acc[f][r] + bqv[f]) * invR[nn];
            unsigned gs = gh | (gl ^ (unsigned)nn);
            qebL[nn * 640 + gs * 8 + (d & 7)] = (ushort)bfr_(qv);
        }
    }
    __syncthreads();

    // ---- phase S: scores = scale * QE @ wkn^T ----
    f32x4 a3[3];
#pragma unroll
    for (int f = 0; f < 3; ++f) a3[f] = (f32x4){0.f, 0.f, 0.f, 0.f};
    for (int k0 = 0; k0 < NDIM; k0 += 32) {
        unsigned g = (unsigned)((k0 >> 3) + lh);
        unsigned gs = (g & ~15u) | ((g & 15u) ^ (unsigned)l15);
        s16x8 af = *(const s16x8*)&qebL[l15 * 640 + gs * 8];
#pragma unroll
        for (int f = 0; f < 3; ++f) {
            int kk = (wv * 3 + f) * 16 + l15;
            s16x8 bv = *(const s16x8*)&wknb[((size_t)t * 384 + kk) * NDIM + k0 + lh * 8];
            a3[f] = __builtin_amdgcn_mfma_f32_16x16x32_bf16(af, bv, a3[f], 0, 0, 0);
        }
    }
    float sat = scale_att[t];
#pragma unroll
    for (int f = 0; f < 3; ++f) {
        int kk = (wv * 3 + f) * 16 + l15;
#pragma unroll
        for (int r = 0; r < 4; ++r) scL[(lh * 4 + r) * 384 + kk] = sat * a3[f][r];
    }
    __syncthreads();
    {   // softmax: 16 rows x 32 threads
        int row = tid >> 5, li = tid & 31;
        float e[12]; float mx = -1e30f;
#pragma unroll
        for (int j = 0; j < 12; ++j) {
            int k = li + 32 * j;
            float v = (k < NCLS) ? scL[row * 384 + k] : -1e30f;
            e[j] = v; mx = fmaxf(mx, v);
        }
#pragma unroll
        for (int off = 1; off < 32; off <<= 1) mx = fmaxf(mx, __shfl_xor(mx, off, 64));
        float se = 0.f;
#pragma unroll
        for (int j = 0; j < 12; ++j) {
            int k = li + 32 * j;
            float ev = (k < NCLS) ? expf(e[j] - mx) : 0.f;
            e[j] = ev; se += ev;
        }
#pragma unroll
        for (int off = 1; off < 32; off <<= 1) se += __shfl_xor(se, off, 64);
        float is = 1.f / se;
#pragma unroll
        for (int j = 0; j < 12; ++j) scL[row * 384 + li + 32 * j] = e[j] * is;
    }
    __syncthreads();
    // pack att -> attL bf16 swizzled
    for (int idx = tid; idx < 3072; idx += 512) {
        int row = idx / 192, pp = idx - row * 192;
        int k2 = 2 * pp;
        unsigned g = (unsigned)(k2 >> 3);
        unsigned gs = (g & ~15u) | ((g & 15u) ^ (unsigned)row);
        attL[row * 192 + gs * 4 + ((k2 >> 1) & 3)] = pkbf_(scL[row * 384 + k2], scL[row * 384 + k2 + 1]);
    }
    __syncthreads();

    // ---- phase W: wtb = att @ wbnT ; comb epilogue ----
    f32x4 a4[5];
#pragma unroll
    for (int f = 0; f < 5; ++f) a4[f] = (f32x4){0.f, 0.f, 0.f, 0.f};
    const ushort* attp = (const ushort*)attL;
    for (int k0 = 0; k0 < 384; k0 += 32) {
        unsigned g = (unsigned)((k0 >> 3) + lh);
        unsigned gs = (g & ~15u) | ((g & 15u) ^ (unsigned)l15);
        s16x8 af = *(const s16x8*)&attp[l15 * 384 + gs * 8];
#pragma unroll
        for (int f = 0; f < 5; ++f) {
            int c = (wv * 5 + f) * 16 + l15;
            s16x8 bv = *(const s16x8*)&wbnT[((size_t)t * NDIM + c) * 384 + k0 + lh * 8];
            a4[f] = __builtin_amdgcn_mfma_f32_16x16x32_bf16(af, bv, a4[f], 0, 0, 0);
        }
    }
    float ln2 = lamn[t] * lamn[t], lb2 = lamb[t] * lamb[t];
#pragma unroll
    for (int f = 0; f < 5; ++f) {
        int c = (wv * 5 + f) * 16 + l15;
#pragma unroll
        for (int r = 0; r < 4; ++r) {
            int ng = n0 + lh * 4 + r;
            if (ng < 100) {
                size_t o = ((size_t)ng * NT + t) * NDIM + c;
                comb[o] = ln2 * sptn[o] + lb2 * a4[f][r];
            }
        }
    }
}

// ---------------------------------------------------------------- k_proto
__global__ __launch_bounds__(128) void k_proto(const float* __restrict__ comb,
    float* __restrict__ proto)
{
    int wt = blockIdx.x;
    int w = wt >> 3, t = wt & 7;
    int tid = threadIdx.x, lane = tid & 63, wv = tid >> 6;
    __shared__ float red[2];
    float mv[5]; float ss = 0.f;
#pragma unroll
    for (int m = 0; m < 5; ++m) {
        int c = tid + 128 * m;
        float a = 0.f;
#pragma unroll
        for (int s = 0; s < NSHOT; ++s)
            a += comb[(((size_t)(s * NWAY + w)) * NT + t) * NDIM + c];
        a *= 0.2f;
        mv[m] = a; ss += a * a;
    }
    ss = waveReduceSum(ss);
    if (lane == 0) red[wv] = ss;
    __syncthreads();
    float inv = invl2_(red[0] + red[1]);
#pragma unroll
    for (int m = 0; m < 5; ++m) proto[(size_t)wt * NDIM + tid + 128 * m] = mv[m] * inv;
}

// ---------------------------------------------------------------- k_query3
// grid 2000 (1D): q = (bid>>4)*8 + (bid&7), hf = (bid>>3)&1.
// Blocks b and b^8 share q AND have equal bid%8 -> SAME XCD, 8 dispatch slots
// apart -> the pair's qry slice is fetched from HBM once (TCC miss-merge + L2).
__global__ __launch_bounds__(512, 4) void k_query3(const float* __restrict__ qry,
    const ushort* __restrict__ filtb, const float* __restrict__ proto,
    const float* __restrict__ wgt, float* __restrict__ out)
{
    int bid = blockIdx.x;
    int q = (bid >> 4) * 8 + (bid & 7);
    int hf = (bid >> 3) & 1;
    int tid = threadIdx.x, lane = tid & 63, wv = tid >> 6;     // 8 waves
    int l15 = lane & 15, lh = lane >> 4;
    const float* qbase = qry + (size_t)q * NDIM * NXY;
    __shared__ __align__(16) unsigned actL[80 * 64];           // 20 KB swizzled
    __shared__ float simacc[8 * 80 * 2];                       // 5 KB
    __shared__ float simF[80];

    // ---------------- phase 1: act' (direct gather, no barriers) ----------------
    int xy = wv * 16 + l15;
    const float* colb = qbase + (xy < NXY ? xy : 0);
    f32x4 acc[5];
#pragma unroll
    for (int m = 0; m < 5; ++m) acc[m] = (f32x4){0.f, 0.f, 0.f, 0.f};
    float ssq = 0.f;
    for (int c0 = 0; c0 < NDIM; c0 += 32) {
        float v[8];
#pragma unroll
        for (int j = 0; j < 8; ++j) {
            v[j] = colb[(size_t)(c0 + lh * 8 + j) * NXY];
            ssq += v[j] * v[j];
        }
        union { unsigned u[4]; s16x8 x; } bf;
#pragma unroll
        for (int p = 0; p < 4; ++p) bf.u[p] = pkbf_(v[2 * p], v[2 * p + 1]);
#pragma unroll
        for (int m = 0; m < 5; ++m) {
            s16x8 af = *(const s16x8*)&filtb[(size_t)(hf * 80 + m * 16 + l15) * NDIM + c0 + lh * 8];
            acc[m] = __builtin_amdgcn_mfma_f32_16x16x32_bf16(af, bf.x, acc[m], 0, 0, 0);
        }
    }
    ssq += __shfl_xor(ssq, 16, 64);
    ssq += __shfl_xor(ssq, 32, 64);
    float inv = (xy < NXY) ? invl2_(ssq) : 0.f;
    for (int i = tid; i < 8 * 80 * 2; i += 512) simacc[i] = 0.f;
    {
        unsigned xg = (unsigned)(xy >> 3);
        unsigned xo = (unsigned)(xy & 7) * 2;
#pragma unroll
        for (int m = 0; m < 5; ++m) {
#pragma unroll
            for (int r = 0; r < 4; ++r) {
                int row = m * 16 + lh * 4 + r;    // 0..79 local
                float a = sigmoidf_(acc[m][r] * inv) * inv;
                unsigned g = (xg ^ (unsigned)row) & 15u;
                *(ushort*)((char*)actL + (size_t)row * 256 + g * 16 + xo) = (ushort)bfr_(a);
            }
        }
    }
    __syncthreads();

    // ---------------- phase 2: pool + sim ----------------
    int ns = wv & 3, a_ = wv >> 2;                // m = 3*a_ + i ; count 3 - a_
    float dacc[3][4], sacc[3][4];
#pragma unroll
    for (int i = 0; i < 3; ++i)
#pragma unroll
        for (int r = 0; r < 4; ++r) { dacc[i][r] = 0.f; sacc[i][r] = 0.f; }

    for (int c0 = 0; c0 < NDIM; c0 += 64) {
        int cb = c0 + ns * 16 + l15;
        const float* rp = qbase + (size_t)cb * NXY;
        s16x8 bfv[4];
#pragma unroll
        for (int kk = 0; kk < 4; ++kk) {
            if (kk == 3 && lh == 3) {
                union { unsigned u[4]; s16x8 v; } r;
                r.u[0] = pkbf_(rp[120], 0.f); r.u[1] = 0u; r.u[2] = 0u; r.u[3] = 0u;
                bfv[kk] = r.v;
            } else {
                bfv[kk] = cvt8_(rp + kk * 32 + lh * 8);
            }
        }
#pragma unroll
        for (int i = 0; i < 3; ++i) {
            if (i < 3 - a_) {
                int m = 3 * a_ + i;
                f32x4 c4 = (f32x4){0.f, 0.f, 0.f, 0.f};
#pragma unroll
                for (int kk = 0; kk < 4; ++kk) {
                    unsigned g = ((unsigned)(kk * 4 + lh) ^ (unsigned)l15) & 15u;
                    s16x8 af = *(const s16x8*)&actL[(m * 16 + l15) * 64 + g * 4];
                    c4 = __builtin_amdgcn_mfma_f32_16x16x32_bf16(af, bfv[kk], c4, 0, 0, 0);
                }
#pragma unroll
                for (int r = 0; r < 4; ++r) {
                    float p = proto[(size_t)(hf * 80 + m * 16 + lh * 4 + r) * NDIM + cb];
                    dacc[i][r] += c4[r] * p;
                    sacc[i][r] += c4[r] * c4[r];
                }
            }
        }
    }
#pragma unroll
    for (int i = 0; i < 3; ++i) {
        if (i < 3 - a_) {
#pragma unroll
            for (int r = 0; r < 4; ++r) {
                float d = dacc[i][r], s2 = sacc[i][r];
#pragma unroll
                for (int off = 1; off < 16; off <<= 1) {
                    d += __shfl_xor(d, off, 64);
                    s2 += __shfl_xor(s2, off, 64);
                }
                if (l15 == 0) {
                    int wtl = (3 * a_ + i) * 16 + lh * 4 + r;
                    simacc[(wv * 80 + wtl) * 2 + 0] = d;
                    simacc[(wv * 80 + wtl) * 2 + 1] = s2;
                }
            }
        }
    }
    __syncthreads();
    if (tid < 80) {
        float d = 0.f, s2 = 0.f;
#pragma unroll
        for (int w8 = 0; w8 < 8; ++w8) {
            d += simacc[(w8 * 80 + tid) * 2 + 0];
            s2 += simacc[(w8 * 80 + tid) * 2 + 1];
        }
        simF[tid] = d * invl2_(s2);
    }
    __syncthreads();
    if (tid < 10) {
        int w = hf * 10 + tid;
        float lg = 0.f;
#pragma unroll
        for (int t = 0; t < NT; ++t) lg += simF[tid * NT + t] * wgt[w * NT + t];
        out[q * NWAY + w] = 2.0f * lg;   // / TEMP
    }
}

extern "C" void kernel_launch(void* const* d_in, const int* in_sizes, int n_in,
                              void* d_out, int out_size, void* d_ws, size_t ws_size,
                              hipStream_t stream)
{
    const float* spt  = (const float*)d_in[0];
    const float* qry  = (const float*)d_in[1];
    const float* l2v  = (const float*)d_in[2];
    const float* w1   = (const float*)d_in[3];
    const float* b1   = (const float*)d_in[4];
    const float* w2   = (const float*)d_in[5];
    const float* b2   = (const float*)d_in[6];
    const float* wb   = (const float*)d_in[7];
    const float* wq   = (const float*)d_in[8];
    const float* bq   = (const float*)d_in[9];
    const float* wk   = (const float*)d_in[10];
    const float* sat  = (const float*)d_in[11];
    const float* lamn = (const float*)d_in[12];
    const float* lamb = (const float*)d_in[13];
    const float* wt1  = (const float*)d_in[14];
    const float* bt1  = (const float*)d_in[15];
    const float* wt2  = (const float*)d_in[16];
    const float* bt2  = (const float*)d_in[17];
    const float* tb   = (const float*)d_in[18];
    const float* tl1  = (const float*)d_in[19];
    const float* tl2  = (const float*)d_in[20];

    float* ws = (float*)d_ws;
    ushort*  filtb  = (ushort*)ws;                 // 51,200 f
    float*   wgt    = ws + 51200;                  // 160
    ushort*  wqb    = (ushort*)(ws + 51360);       // 1,638,400 f
    ushort*  wknb   = (ushort*)(ws + 1689760);     // 983,040 f
    ushort*  wbnT   = (ushort*)(ws + 2672800);     // 983,040 f
    float*   invb   = ws + 3655840;                // 2,816
    ushort*  xb     = (ushort*)(ws + 3658656);     // 286,720 f
    float*   sptn   = ws + 3945376;                // 512,000
    float*   combv  = ws + 4457376;                // 512,000
    float*   proto  = ws + 4969376;                // 102,400
    float*   outp   = (float*)d_out;               // ws total ~5.07M floats (~20 MB)

    hipLaunchKernelGGL(k_prepw,    dim3(7396),     dim3(256), 0, stream,
                       l2v, w1, b1, w2, b2, wq, wk, wb, wt1, bt1, wt2, bt2, tb, tl1, tl2,
                       filtb, wgt, (unsigned*)wqb, wknb, invb);
    hipLaunchKernelGGL(k_wbT,      dim3(6, 10, 8), dim3(256), 0, stream, wb, invb, (unsigned*)wbnT);
    hipLaunchKernelGGL(k_support2, dim3(20, 5),    dim3(512), 0, stream, spt, filtb, sptn, xb);
    hipLaunchKernelGGL(k_qatt,     dim3(8, 7),     dim3(512), 0, stream,
                       xb, wqb, bq, wknb, wbnT, sptn, sat, lamn, lamb, combv);
    hipLaunchKernelGGL(k_proto,    dim3(160),      dim3(128), 0, stream, combv, proto);
    hipLaunchKernelGGL(k_query3,   dim3(2000),     dim3(512), 0, stream,
                       qry, filtb, proto, wgt, outp);
}